// Round 5
// baseline (669.799 us; speedup 1.0000x reference)
//
#include <hip/hip_runtime.h>
#include <cstdint>
#include <cstddef>

#define NB 8
#define CIN 256
#define HWX 4096
#define CF 256
#define CA 128
#define CT 384

typedef __attribute__((ext_vector_type(8))) _Float16 half8;
typedef __attribute__((ext_vector_type(8))) short short8;
typedef __attribute__((ext_vector_type(4))) short s16x4;
typedef __attribute__((ext_vector_type(4))) float f32x4;
typedef __attribute__((ext_vector_type(4))) unsigned int u32x4;
typedef __attribute__((ext_vector_type(2))) unsigned int u32x2;

// workspace layout (bytes)
#define OFF_WH   0                              // 384*256 fp16 folded weights
#define OFF_BIAS (CT*CIN*2)                     // 384 fp32 folded bias
#define OFF_FEAT (OFF_BIAS + CT*4)              // [n][256][4096] fp16
#define OFF_Q    (OFF_FEAT + NB*CF*HWX*2)       // [n][4096][128] fp16
#define OFF_NORM (OFF_Q + NB*HWX*CA*2)          // [n][4096] fp32 row norms of q
#define OFF_G    (OFF_NORM + NB*HWX*4)          // [n] uint (max norm bits)

__device__ inline unsigned short f16_bits(float f) {
  _Float16 h = (_Float16)f;
  return __builtin_bit_cast(unsigned short, h);
}
__device__ inline half8 ld_half8(const unsigned short* p) {
  short8 r = *(const short8*)p;
  return __builtin_bit_cast(half8, r);
}

// async global->LDS, 16B per lane; LDS side must be lane-linear (m104/m108),
// swizzle goes on the GLOBAL address.
__device__ inline void g2l16(const void* g, void* l) {
  __builtin_amdgcn_global_load_lds(
      (const __attribute__((address_space(1))) unsigned int*)g,
      (__attribute__((address_space(3))) unsigned int*)l, 16, 0, 0);
}

// ---------------- kernel 1: fold BN into fp16 weights (+ zero G) ----------------
__global__ __launch_bounds__(256) void fold_bn_k(
    const float* __restrict__ rw, const float* __restrict__ rg,
    const float* __restrict__ rb, const float* __restrict__ rm, const float* __restrict__ rv,
    const float* __restrict__ aw, const float* __restrict__ ag,
    const float* __restrict__ ab2, const float* __restrict__ am, const float* __restrict__ av,
    unsigned short* __restrict__ wh, float* __restrict__ bias, unsigned* __restrict__ Gmax) {
  int o = blockIdx.x, k = threadIdx.x;
  if (o == 0 && k < NB) Gmax[k] = 0u;
  const float* wsrc; float g, b, m, v;
  if (o < CF) { wsrc = rw + (size_t)o*CIN; g = rg[o]; b = rb[o]; m = rm[o]; v = rv[o]; }
  else { int oa = o - CF; wsrc = aw + (size_t)oa*CIN; g = ag[oa]; b = ab2[oa]; m = am[oa]; v = av[oa]; }
  float inv = g / sqrtf(v + 1e-5f);
  wh[(size_t)o*CIN + k] = f16_bits(wsrc[k] * inv);
  if (k == 0) bias[o] = b - m*inv;
}

// ---------------- kernel 2: fp16 MFMA conv(1x1)+BN+ReLU ----------------
// grid 512 = 8n x 64 pos-tiles(64); 512 thr (8 waves); 2 blocks/CU.
// Block tile: [64 pos] x [384 oc] x K=256. Wave w owns oc slab [w*48, w*48+48).
// R3 delta: B3 (weight) frags register-prefetched one ks ahead -- the old code issued
// 3 synchronous L2 loads per ks consumed immediately by MFMA (exposed ~200-400cy L2
// latency every K-step; same mechanism that collapsed R1's flash QK).
__global__ __launch_bounds__(512, 4) void conv_k(
    const float* __restrict__ x, const unsigned short* __restrict__ wh,
    const float* __restrict__ bias, unsigned short* __restrict__ feat,
    unsigned short* __restrict__ q, float* __restrict__ normq,
    unsigned* __restrict__ Gmax) {
  __shared__ unsigned short sX[64*256];   // xT [64 pos][256 k] fp16, swizzled; 32KB
  unsigned short (*sQr)[136] = (unsigned short(*)[136])sX;  // aliased after K-loop
  int b = blockIdx.x;
  int n = b & 7, pt0 = b >> 3;
  int p0 = pt0 * 64;
  int t = threadIdx.x;
  int w = t >> 6, lane = t & 63, quad = lane >> 4, col = lane & 15;
  const float* xn = x + (size_t)n*CIN*HWX;

  // stage x tile [256 k][64 pos] -> sX transposed fp16, swizzled.
  #pragma unroll
  for (int pass=0; pass<4; pass++) {
    int idx = pass*512 + t;
    int kp = idx >> 4, c4 = idx & 15;
    f32x4 a = *(const f32x4*)(xn + (size_t)(2*kp)*HWX + p0 + c4*4);
    f32x4 c = *(const f32x4*)(xn + (size_t)(2*kp+1)*HWX + p0 + c4*4);
    int unit = kp >> 2, off = kp & 3;
    #pragma unroll
    for (int j=0;j<4;j++) {
      int pos = c4*4 + j;
      unsigned dd = (unsigned)f16_bits(a[j]) | ((unsigned)f16_bits(c[j]) << 16);
      *(unsigned*)&sX[pos*256 + ((unit ^ (pos & 31)) << 3) + off*2] = dd;
    }
  }
  __syncthreads();

  f32x4 fzero = {0.f,0.f,0.f,0.f};
  f32x4 acc[4][3];                  // [pos-tile][oc-tile]
  #pragma unroll
  for (int pt=0;pt<4;pt++)
    #pragma unroll
    for (int ot=0;ot<3;ot++) acc[pt][ot] = fzero;

  int ocb = w*48;
  half8 B3[3];
  #pragma unroll
  for (int ot=0;ot<3;ot++)
    B3[ot] = ld_half8(wh + (size_t)(ocb + ot*16 + col)*CIN + quad*8);   // ks=0
  #pragma unroll
  for (int ks=0; ks<8; ks++) {
    half8 B3n[3];
    if (ks < 7) {
      #pragma unroll
      for (int ot=0;ot<3;ot++)
        B3n[ot] = ld_half8(wh + (size_t)(ocb + ot*16 + col)*CIN + (ks+1)*32 + quad*8);
    }
    half8 A4[4];
    #pragma unroll
    for (int pt=0;pt<4;pt++) {
      int pos = pt*16 + col;
      A4[pt] = ld_half8(&sX[pos*256 + (((ks*4 + quad) ^ (pos & 31)) << 3)]);
    }
    #pragma unroll
    for (int pt=0;pt<4;pt++)
      #pragma unroll
      for (int ot=0;ot<3;ot++)
        acc[pt][ot] = __builtin_amdgcn_mfma_f32_16x16x32_f16(A4[pt], B3[ot], acc[pt][ot], 0, 0, 0);
    if (ks < 7) {
      #pragma unroll
      for (int ot=0;ot<3;ot++) B3[ot] = B3n[ot];
    }
  }
  __syncthreads();   // all sX reads done; region reused as sQr

  // epilogue: bias+ReLU; feat (oc<256) direct 8B stores; q (oc>=256) via LDS transpose
  float bv[3];
  #pragma unroll
  for (int ot=0;ot<3;ot++) bv[ot] = bias[ocb + ot*16 + col];
  #pragma unroll
  for (int pt=0;pt<4;pt++)
    #pragma unroll
    for (int ot=0;ot<3;ot++) {
      int oc = ocb + ot*16 + col;
      alignas(8) unsigned short u4[4];
      #pragma unroll
      for (int r=0;r<4;r++)
        u4[r] = f16_bits(fmaxf(acc[pt][ot][r] + bv[ot], 0.f));
      if (oc < CF) {
        *(u32x2*)(feat + (size_t)n*CF*HWX + (size_t)oc*HWX + p0 + pt*16 + quad*4) =
            *(const u32x2*)u4;
      } else {
        int cc = oc - CF;
        #pragma unroll
        for (int r=0;r<4;r++)
          sQr[pt*16 + quad*4 + r][cc] = u4[r];
      }
    }
  __syncthreads();

  // q readback + row norms: t<256: pos = t>>2 (64), seg = t&3 (32 c each)
  if (t < 256) {
    int pos = t >> 2, seg = t & 3;
    const unsigned short* src = &sQr[pos][seg*32];
    unsigned short* dst = q + ((size_t)n*HWX + p0 + pos)*CA + seg*32;
    float s2 = 0.f;
    #pragma unroll
    for (int u=0;u<4;u++) {
      short8 v = *(const short8*)(src + u*8);
      *(short8*)(dst + u*8) = v;
      half8 h = __builtin_bit_cast(half8, v);
      #pragma unroll
      for (int e=0;e<8;e++) { float fe = (float)h[e]; s2 += fe*fe; }
    }
    s2 += __shfl_xor(s2, 1, 64);
    s2 += __shfl_xor(s2, 2, 64);
    if (seg == 0) normq[(size_t)n*HWX + p0 + pos] = sqrtf(s2);
    float mx = s2;
    mx = fmaxf(mx, __shfl_xor(mx, 4, 64));
    mx = fmaxf(mx, __shfl_xor(mx, 8, 64));
    mx = fmaxf(mx, __shfl_xor(mx, 16, 64));
    mx = fmaxf(mx, __shfl_xor(mx, 32, 64));
    if (lane == 0) atomicMax(Gmax + n, __float_as_uint(sqrtf(mx)));
  }
}

// ---------------- kernel 3: flash attention, BN=64, 3 blocks/CU ----------------
// grid 512 = 8n x 64 i-tiles (BM=64); 512 thr (8 waves).
// R3 structural change: j-tile halved 128->64. LDS/block 50.7KB -> 25.9KB
// (sQ 16KB + sP[64][68] 8.7KB), so 3 blocks/CU co-reside (launch_bounds(512,6),
// VGPR cap ~85). R2 showed MfmaUtil pinned at 24% with conflicts=0 and 2 lockstep
// blocks/CU: the limiter is phase serialization (QK->softmax->PV serial per block,
// barriers align all 8 waves). 3 independent barrier groups + 6 waves/SIMD create
// the phase drift that lets MFMA/VALU/LDS pipes overlap across blocks.
// Same wq/wh split, same swizzles; pad 68 keeps the verified (stride mod 32 == 2)
// conflict-free bank pattern from R2 (measured SQ_LDS_BANK_CONFLICT == 0).
__global__ __launch_bounds__(512, 6) void flash_k(
    const unsigned short* __restrict__ q, const unsigned short* __restrict__ feat,
    const float* __restrict__ mask, const float* __restrict__ normq,
    const unsigned* __restrict__ Gmax, float* __restrict__ out) {
  __shared__ alignas(16) unsigned short sQ[64*128];   // j-tile q fp16, octet-swizzled
  __shared__ alignas(16) unsigned short sP[64][68];   // P (A-layout), pad 68
  __shared__ float sM[64];
  __shared__ float sL[2][64];
  int b = blockIdx.x;
  int n = b & 7, it = b >> 3;         // n == XCD for L2 locality
  int i0 = it * 64;
  int t = threadIdx.x;
  int w = t >> 6, lane = t & 63, quad = lane >> 4, col = lane & 15;
  int wq = w & 3, wh = w >> 2;
  const unsigned short* q_n = q + (size_t)n*HWX*CA;
  const unsigned short* f_n = feat + (size_t)n*CF*HWX;
  const float* m_n = mask + (size_t)n*HWX;
  const int rloc = t >> 4 & 31, oct16 = t & 15;
  const float inv_s = 1.0f/(1e-8f + sqrtf(128.0f));

  auto stage_Q = [&](int j0) {
    #pragma unroll
    for (int c=0;c<2;c++) {
      int row = c*32 + rloc;
      int og = oct16 ^ (row & 15);
      g2l16(q_n + (size_t)(j0+row)*CA + og*8, &sQ[(size_t)row*128 + oct16*8]);
    }
    if (t < 16) g2l16(m_n + j0 + t*4, &sM[t*4]);
  };

  // A fragments for QK (this wave's 16 i rows), held in registers for all iters
  half8 ah[4];
  {
    int arow = i0 + wq*16 + col;
    #pragma unroll
    for (int ks=0; ks<4; ks++)
      ah[ks] = ld_half8(q_n + (size_t)arow*CA + ks*32 + quad*8);
  }
  // per-row exp shift: C_i - 5 (max-free softmax via Cauchy-Schwarz bound)
  float Gn = __uint_as_float(Gmax[n]);
  float cvals[4];
  #pragma unroll
  for (int r=0;r<4;r++)
    cvals[r] = normq[(size_t)n*HWX + i0 + wq*16 + quad*4 + r] * Gn * inv_s - 5.0f;

  f32x4 fzero = {0.f,0.f,0.f,0.f};
  f32x4 o[4][2];                      // [i-group][c-tile], c-slab = w*32
  #pragma unroll
  for (int ig=0;ig<4;ig++) { o[ig][0] = fzero; o[ig][1] = fzero; }
  float lrun[4] = {0.f,0.f,0.f,0.f};

  stage_Q(0);
  #pragma unroll 1
  for (int ji = 0; ji < 64; ji++) {
    int j0 = ji*64;
    __syncthreads();                  // A: sQ(ji)+sM(ji) ready; PV(ji-1) done with sP

    // prefetch all PV B-frags (K=64: ks2=0,1); consumed after barrier B --
    // L2 latency hides under QK+softmax. 16 VGPRs live across QK.
    half8 bF[2][2];
    #pragma unroll
    for (int ks2=0;ks2<2;ks2++)
      #pragma unroll
      for (int ct=0;ct<2;ct++) {
        int c = w*32 + ct*16 + col;
        bF[ks2][ct] = ld_half8(f_n + (size_t)c*HWX + j0 + ks2*32 + quad*8);
      }

    // ---- QK^T: S[16 i x 32 j] (this wave's j-half), 2 indep chains of 4
    f32x4 s[2];
    s[0] = fzero; s[1] = fzero;
    __builtin_amdgcn_s_setprio(1);
    #pragma unroll
    for (int jt=0;jt<2;jt++) {
      int rowj = wh*32 + jt*16 + col;
      #pragma unroll
      for (int ks=0; ks<4; ks++) {
        int slot = (ks*4 + quad) ^ (rowj & 15);
        half8 bq = ld_half8(&sQ[rowj*128 + slot*8]);
        s[jt] = __builtin_amdgcn_mfma_f32_16x16x32_f16(ah[ks], bq, s[jt], 0, 0, 0);
      }
    }
    __builtin_amdgcn_s_setprio(0);

    // ---- max-free softmax: P = exp(E*inv_s + maskterm - C_i + 5); l += P
    #pragma unroll
    for (int jt=0;jt<2;jt++) {
      float mj = (sM[wh*32 + jt*16 + col] - 1.f) * 1e8f;
      #pragma unroll
      for (int r=0;r<4;r++) {
        float p = __expf(s[jt][r]*inv_s + mj - cvals[r]);
        lrun[r] += p;
        sP[wq*16 + quad*4 + r][wh*32 + jt*16 + col] = f16_bits(p);
      }
    }

    __syncthreads();                  // B: sP visible; QK reads of sQ done
    if (ji + 1 < 64) stage_Q(j0+64);  // overlaps PV, drained at next barrier A

    // ---- PV: O[64 i x 32 c] for this wave's c-slab, K=64
    __builtin_amdgcn_s_setprio(1);
    #pragma unroll
    for (int ks2=0; ks2<2; ks2++) {
      half8 aP[4];
      #pragma unroll
      for (int ig=0;ig<4;ig++) {
        const unsigned short* pp = &sP[ig*16 + col][ks2*32 + quad*8];
        s16x4 lo = *(const s16x4*)pp;        // rows 8B-aligned (136B stride)
        s16x4 hi = *(const s16x4*)(pp + 4);
        short8 vv = __builtin_shufflevector(lo, hi, 0,1,2,3,4,5,6,7);
        aP[ig] = __builtin_bit_cast(half8, vv);
      }
      #pragma unroll
      for (int ct=0;ct<2;ct++) {
        #pragma unroll
        for (int ig=0;ig<4;ig++)
          o[ig][ct] = __builtin_amdgcn_mfma_f32_16x16x32_f16(aP[ig], bF[ks2][ct], o[ig][ct], 0, 0, 0);
      }
    }
    __builtin_amdgcn_s_setprio(0);
  }

  // ---- final l: reduce 16 j-cols in-wave, combine halves via LDS
  #pragma unroll
  for (int r=0;r<4;r++) {
    float ss = lrun[r];
    ss += __shfl_xor(ss, 1, 64);
    ss += __shfl_xor(ss, 2, 64);
    ss += __shfl_xor(ss, 4, 64);
    ss += __shfl_xor(ss, 8, 64);
    lrun[r] = ss;
  }
  #pragma unroll
  for (int r=0;r<4;r++)
    if (col == 0) sL[wh][wq*16 + quad*4 + r] = lrun[r];
  __syncthreads();
  #pragma unroll
  for (int ig=0;ig<4;ig++) {
    int base = ig*16 + quad*4;
    f32x4 l0 = *(const f32x4*)&sL[0][base];
    f32x4 l1 = *(const f32x4*)&sL[1][base];
    f32x4 mv = *(const f32x4*)(m_n + i0 + base);
    f32x4 minv;
    #pragma unroll
    for (int r=0;r<4;r++) minv[r] = mv[r] / (l0[r] + l1[r]);
    #pragma unroll
    for (int ct=0;ct<2;ct++) {
      int c = w*32 + ct*16 + col;
      f32x4 v;
      #pragma unroll
      for (int r=0;r<4;r++) v[r] = o[ig][ct][r] * minv[r];
      *(f32x4*)(out + ((size_t)n*CF + c)*HWX + i0 + base) = v;
    }
  }
}

extern "C" void kernel_launch(void* const* d_in, const int* in_sizes, int n_in,
                              void* d_out, int out_size, void* d_ws, size_t ws_size,
                              hipStream_t stream) {
  const float* x    = (const float*)d_in[0];
  const float* mask = (const float*)d_in[1];
  const float* rw   = (const float*)d_in[2];
  const float* rg   = (const float*)d_in[3];
  const float* rb   = (const float*)d_in[4];
  const float* rm   = (const float*)d_in[5];
  const float* rv   = (const float*)d_in[6];
  const float* aw   = (const float*)d_in[7];
  const float* ag   = (const float*)d_in[8];
  const float* ab   = (const float*)d_in[9];
  const float* am   = (const float*)d_in[10];
  const float* av   = (const float*)d_in[11];
  float* out = (float*)d_out;
  char* ws = (char*)d_ws;
  unsigned short* wh = (unsigned short*)(ws + OFF_WH);
  float* bias = (float*)(ws + OFF_BIAS);
  unsigned short* feat = (unsigned short*)(ws + OFF_FEAT);
  unsigned short* q    = (unsigned short*)(ws + OFF_Q);
  float* normq = (float*)(ws + OFF_NORM);
  unsigned* Gmax = (unsigned*)(ws + OFF_G);

  hipLaunchKernelGGL(fold_bn_k, dim3(CT), dim3(CIN), 0, stream,
                     rw, rg, rb, rm, rv, aw, ag, ab, am, av, wh, bias, Gmax);
  hipLaunchKernelGGL(conv_k, dim3(512), dim3(512), 0, stream,
                     x, wh, bias, feat, q, normq, Gmax);
  hipLaunchKernelGGL(flash_k, dim3(512), dim3(512), 0, stream,
                     q, feat, mask, normq, Gmax, out);
}

// Round 6
// 389.424 us; speedup vs baseline: 1.7200x; 1.7200x over previous
//
#include <hip/hip_runtime.h>
#include <cstdint>
#include <cstddef>

#define NB 8
#define CIN 256
#define HWX 4096
#define CF 256
#define CA 128
#define CT 384

typedef __attribute__((ext_vector_type(8))) _Float16 half8;
typedef __attribute__((ext_vector_type(8))) short short8;
typedef __attribute__((ext_vector_type(4))) short s16x4;
typedef __attribute__((ext_vector_type(4))) float f32x4;
typedef __attribute__((ext_vector_type(4))) unsigned int u32x4;
typedef __attribute__((ext_vector_type(2))) unsigned int u32x2;

// workspace layout (bytes)
#define OFF_WH   0                              // 384*256 fp16 folded weights
#define OFF_BIAS (CT*CIN*2)                     // 384 fp32 folded bias
#define OFF_FEAT (OFF_BIAS + CT*4)              // [n][256][4096] fp16
#define OFF_Q    (OFF_FEAT + NB*CF*HWX*2)       // [n][4096][128] fp16
#define OFF_NORM (OFF_Q + NB*HWX*CA*2)          // [n][4096] fp32 row norms of q
#define OFF_G    (OFF_NORM + NB*HWX*4)          // [n] uint (max norm bits)

__device__ inline unsigned short f16_bits(float f) {
  _Float16 h = (_Float16)f;
  return __builtin_bit_cast(unsigned short, h);
}
__device__ inline half8 ld_half8(const unsigned short* p) {
  short8 r = *(const short8*)p;
  return __builtin_bit_cast(half8, r);
}

// async global->LDS, 16B per lane; LDS side must be lane-linear (m104/m108),
// swizzle goes on the GLOBAL address.
__device__ inline void g2l16(const void* g, void* l) {
  __builtin_amdgcn_global_load_lds(
      (const __attribute__((address_space(1))) unsigned int*)g,
      (__attribute__((address_space(3))) unsigned int*)l, 16, 0, 0);
}

// ---------------- kernel 1: fold BN into fp16 weights (+ zero G) ----------------
__global__ __launch_bounds__(256) void fold_bn_k(
    const float* __restrict__ rw, const float* __restrict__ rg,
    const float* __restrict__ rb, const float* __restrict__ rm, const float* __restrict__ rv,
    const float* __restrict__ aw, const float* __restrict__ ag,
    const float* __restrict__ ab2, const float* __restrict__ am, const float* __restrict__ av,
    unsigned short* __restrict__ wh, float* __restrict__ bias, unsigned* __restrict__ Gmax) {
  int o = blockIdx.x, k = threadIdx.x;
  if (o == 0 && k < NB) Gmax[k] = 0u;
  const float* wsrc; float g, b, m, v;
  if (o < CF) { wsrc = rw + (size_t)o*CIN; g = rg[o]; b = rb[o]; m = rm[o]; v = rv[o]; }
  else { int oa = o - CF; wsrc = aw + (size_t)oa*CIN; g = ag[oa]; b = ab2[oa]; m = am[oa]; v = av[oa]; }
  float inv = g / sqrtf(v + 1e-5f);
  wh[(size_t)o*CIN + k] = f16_bits(wsrc[k] * inv);
  if (k == 0) bias[o] = b - m*inv;
}

// ---------------- kernel 2: fp16 MFMA conv(1x1)+BN+ReLU ----------------
// grid 512 = 8n x 64 pos-tiles(64); 512 thr (8 waves); 2 blocks/CU.
// Block tile: [64 pos] x [384 oc] x K=256. Wave w owns oc slab [w*48, w*48+48).
// R6 delta: Gmax atomics 4/block -> 1/block (LDS-combine the 4 wave maxima).
// 2048 device-scope same-address RMWs arriving in an end-of-kernel burst serialize
// at the owning L2 (~300cy each, 256 per address) -- suspected tail of the stable
// ~112us conv residual. B3 register-prefetch (R3) kept.
__global__ __launch_bounds__(512, 4) void conv_k(
    const float* __restrict__ x, const unsigned short* __restrict__ wh,
    const float* __restrict__ bias, unsigned short* __restrict__ feat,
    unsigned short* __restrict__ q, float* __restrict__ normq,
    unsigned* __restrict__ Gmax) {
  __shared__ unsigned short sX[64*256];   // xT [64 pos][256 k] fp16, swizzled; 32KB
  __shared__ float sGm[4];
  unsigned short (*sQr)[136] = (unsigned short(*)[136])sX;  // aliased after K-loop
  int b = blockIdx.x;
  int n = b & 7, pt0 = b >> 3;
  int p0 = pt0 * 64;
  int t = threadIdx.x;
  int w = t >> 6, lane = t & 63, quad = lane >> 4, col = lane & 15;
  const float* xn = x + (size_t)n*CIN*HWX;

  // stage x tile [256 k][64 pos] -> sX transposed fp16, swizzled.
  #pragma unroll
  for (int pass=0; pass<4; pass++) {
    int idx = pass*512 + t;
    int kp = idx >> 4, c4 = idx & 15;
    f32x4 a = *(const f32x4*)(xn + (size_t)(2*kp)*HWX + p0 + c4*4);
    f32x4 c = *(const f32x4*)(xn + (size_t)(2*kp+1)*HWX + p0 + c4*4);
    int unit = kp >> 2, off = kp & 3;
    #pragma unroll
    for (int j=0;j<4;j++) {
      int pos = c4*4 + j;
      unsigned dd = (unsigned)f16_bits(a[j]) | ((unsigned)f16_bits(c[j]) << 16);
      *(unsigned*)&sX[pos*256 + ((unit ^ (pos & 31)) << 3) + off*2] = dd;
    }
  }
  __syncthreads();

  f32x4 fzero = {0.f,0.f,0.f,0.f};
  f32x4 acc[4][3];                  // [pos-tile][oc-tile]
  #pragma unroll
  for (int pt=0;pt<4;pt++)
    #pragma unroll
    for (int ot=0;ot<3;ot++) acc[pt][ot] = fzero;

  int ocb = w*48;
  half8 B3[3];
  #pragma unroll
  for (int ot=0;ot<3;ot++)
    B3[ot] = ld_half8(wh + (size_t)(ocb + ot*16 + col)*CIN + quad*8);   // ks=0
  #pragma unroll
  for (int ks=0; ks<8; ks++) {
    half8 B3n[3];
    if (ks < 7) {
      #pragma unroll
      for (int ot=0;ot<3;ot++)
        B3n[ot] = ld_half8(wh + (size_t)(ocb + ot*16 + col)*CIN + (ks+1)*32 + quad*8);
    }
    half8 A4[4];
    #pragma unroll
    for (int pt=0;pt<4;pt++) {
      int pos = pt*16 + col;
      A4[pt] = ld_half8(&sX[pos*256 + (((ks*4 + quad) ^ (pos & 31)) << 3)]);
    }
    #pragma unroll
    for (int pt=0;pt<4;pt++)
      #pragma unroll
      for (int ot=0;ot<3;ot++)
        acc[pt][ot] = __builtin_amdgcn_mfma_f32_16x16x32_f16(A4[pt], B3[ot], acc[pt][ot], 0, 0, 0);
    if (ks < 7) {
      #pragma unroll
      for (int ot=0;ot<3;ot++) B3[ot] = B3n[ot];
    }
  }
  __syncthreads();   // all sX reads done; region reused as sQr

  // epilogue: bias+ReLU; feat (oc<256) direct 8B stores; q (oc>=256) via LDS transpose
  float bv[3];
  #pragma unroll
  for (int ot=0;ot<3;ot++) bv[ot] = bias[ocb + ot*16 + col];
  #pragma unroll
  for (int pt=0;pt<4;pt++)
    #pragma unroll
    for (int ot=0;ot<3;ot++) {
      int oc = ocb + ot*16 + col;
      alignas(8) unsigned short u4[4];
      #pragma unroll
      for (int r=0;r<4;r++)
        u4[r] = f16_bits(fmaxf(acc[pt][ot][r] + bv[ot], 0.f));
      if (oc < CF) {
        *(u32x2*)(feat + (size_t)n*CF*HWX + (size_t)oc*HWX + p0 + pt*16 + quad*4) =
            *(const u32x2*)u4;
      } else {
        int cc = oc - CF;
        #pragma unroll
        for (int r=0;r<4;r++)
          sQr[pt*16 + quad*4 + r][cc] = u4[r];
      }
    }
  __syncthreads();

  // q readback + row norms: t<256: pos = t>>2 (64), seg = t&3 (32 c each)
  if (t < 256) {
    int pos = t >> 2, seg = t & 3;
    const unsigned short* src = &sQr[pos][seg*32];
    unsigned short* dst = q + ((size_t)n*HWX + p0 + pos)*CA + seg*32;
    float s2 = 0.f;
    #pragma unroll
    for (int u=0;u<4;u++) {
      short8 v = *(const short8*)(src + u*8);
      *(short8*)(dst + u*8) = v;
      half8 h = __builtin_bit_cast(half8, v);
      #pragma unroll
      for (int e=0;e<8;e++) { float fe = (float)h[e]; s2 += fe*fe; }
    }
    s2 += __shfl_xor(s2, 1, 64);
    s2 += __shfl_xor(s2, 2, 64);
    if (seg == 0) normq[(size_t)n*HWX + p0 + pos] = sqrtf(s2);
    float mx = s2;
    mx = fmaxf(mx, __shfl_xor(mx, 4, 64));
    mx = fmaxf(mx, __shfl_xor(mx, 8, 64));
    mx = fmaxf(mx, __shfl_xor(mx, 16, 64));
    mx = fmaxf(mx, __shfl_xor(mx, 32, 64));
    if (lane == 0) sGm[t >> 6] = sqrtf(mx);
  }
  __syncthreads();
  if (t == 0) {
    float m01 = fmaxf(sGm[0], sGm[1]);
    float m23 = fmaxf(sGm[2], sGm[3]);
    atomicMax(Gmax + n, __float_as_uint(fmaxf(m01, m23)));
  }
}

// ---------------- kernel 3: flash attention, BN=128, two barriers/iter ----------------
// grid 512 = 8n x 64 i-tiles (BM=64); 512 thr (8 waves), 2 blocks/CU, 4 waves/SIMD.
// Proven R2 structure (g2l16 sQ pipeline, pad-132 sP, setprio). R6 delta: QK wave
// assignment 1i x 4j -> 2i x 2j. Old: 4 waves (wq=0..3) with the same wh read
// IDENTICAL sQ B-frags (4x redundant, 128KB/block-iter = largest LDS consumer).
// New: wave (wiq=w&1, wjq=w>>1) computes S[32 i x 32 j]: B-reads 16 -> 8 per wave
// (64KB/block-iter, 2x cut), MFMA count unchanged, sP store bank pattern unchanged
// (conflict-free verified R2). Cost: ah 16->32 regs (total ~116+20 < 128 cap, same
// occupancy tier at launch_bounds(512,4) -- R5 proved the tier cliff is at ~85).
// PV untouched. lrun/sL become per-j-quarter: sL[4][64], final l = sum of 4.
__global__ __launch_bounds__(512, 4) void flash_k(
    const unsigned short* __restrict__ q, const unsigned short* __restrict__ feat,
    const float* __restrict__ mask, const float* __restrict__ normq,
    const unsigned* __restrict__ Gmax, float* __restrict__ out) {
  __shared__ alignas(16) unsigned short sQ[128*128];  // j-tile q fp16, octet-swizzled
  __shared__ alignas(16) unsigned short sP[64][132];  // P (A-layout), pad 132
  __shared__ float sM[128];
  __shared__ float sL[4][64];
  int b = blockIdx.x;
  int n = b & 7, it = b >> 3;         // n == XCD for L2 locality
  int i0 = it * 64;
  int t = threadIdx.x;
  int w = t >> 6, lane = t & 63, quad = lane >> 4, col = lane & 15;
  int wiq = w & 1, wjq = w >> 1;      // QK: i-half (32), j-quarter (32)
  const unsigned short* q_n = q + (size_t)n*HWX*CA;
  const unsigned short* f_n = feat + (size_t)n*CF*HWX;
  const float* m_n = mask + (size_t)n*HWX;
  const int rloc = t >> 4 & 31, oct16 = t & 15;
  const float inv_s = 1.0f/(1e-8f + sqrtf(128.0f));

  auto stage_Q = [&](int j0) {
    #pragma unroll
    for (int c=0;c<4;c++) {
      int row = c*32 + rloc;
      int og = oct16 ^ (row & 15);
      g2l16(q_n + (size_t)(j0+row)*CA + og*8, &sQ[(size_t)row*128 + oct16*8]);
    }
    if (t < 32) g2l16(m_n + j0 + t*4, &sM[t*4]);
  };

  // A fragments for QK (this wave's 32 i rows = 2 tiles), resident all iters
  half8 ah[2][4];
  #pragma unroll
  for (int ip=0; ip<2; ip++) {
    int arow = i0 + wiq*32 + ip*16 + col;
    #pragma unroll
    for (int ks=0; ks<4; ks++)
      ah[ip][ks] = ld_half8(q_n + (size_t)arow*CA + ks*32 + quad*8);
  }
  // per-row exp shift: C_i - 5 (max-free softmax via Cauchy-Schwarz bound)
  float Gn = __uint_as_float(Gmax[n]);
  float cvals[2][4];
  #pragma unroll
  for (int ip=0;ip<2;ip++)
    #pragma unroll
    for (int r=0;r<4;r++)
      cvals[ip][r] = normq[(size_t)n*HWX + i0 + wiq*32 + ip*16 + quad*4 + r] * Gn * inv_s - 5.0f;

  f32x4 fzero = {0.f,0.f,0.f,0.f};
  f32x4 o[4][2];                      // [i-group][c-tile], PV c-slab = w*32
  #pragma unroll
  for (int ig=0;ig<4;ig++) { o[ig][0] = fzero; o[ig][1] = fzero; }
  float lrun[2][4] = {{0.f,0.f,0.f,0.f},{0.f,0.f,0.f,0.f}};

  stage_Q(0);
  #pragma unroll 1
  for (int ji = 0; ji < 32; ji++) {
    int j0 = ji*128;
    __syncthreads();                  // A: sQ(ji)+sM(ji) ready; PV(ji-1) done with sP

    // prefetch PV B-frags for ks2=0,1 (consumed after barrier B; L2 latency hides
    // under QK+softmax). ks2=2,3 loaded at PV start to cap live registers.
    half8 bF01[2][2];
    #pragma unroll
    for (int ks2=0;ks2<2;ks2++)
      #pragma unroll
      for (int ct=0;ct<2;ct++) {
        int c = w*32 + ct*16 + col;
        bF01[ks2][ct] = ld_half8(f_n + (size_t)c*HWX + j0 + ks2*32 + quad*8);
      }

    // ---- QK^T: S[32 i x 32 j] (2x2 tiles); each B-frag feeds 2 MFMAs
    f32x4 s[2][2];
    s[0][0] = fzero; s[0][1] = fzero; s[1][0] = fzero; s[1][1] = fzero;
    __builtin_amdgcn_s_setprio(1);
    #pragma unroll
    for (int jt=0;jt<2;jt++) {
      int rowj = wjq*32 + jt*16 + col;
      #pragma unroll
      for (int ks=0; ks<4; ks++) {
        int slot = (ks*4 + quad) ^ (rowj & 15);
        half8 bq = ld_half8(&sQ[rowj*128 + slot*8]);
        #pragma unroll
        for (int ip=0;ip<2;ip++)
          s[ip][jt] = __builtin_amdgcn_mfma_f32_16x16x32_f16(ah[ip][ks], bq, s[ip][jt], 0, 0, 0);
      }
    }
    __builtin_amdgcn_s_setprio(0);

    // ---- max-free softmax: P = exp(E*inv_s + maskterm - C_i + 5); l += P
    // scalar b16 stores at stride 132 -> conflict-free (quads on banks 0/8/16/24)
    #pragma unroll
    for (int jt=0;jt<2;jt++) {
      float mj = (sM[wjq*32 + jt*16 + col] - 1.f) * 1e8f;
      #pragma unroll
      for (int ip=0;ip<2;ip++)
        #pragma unroll
        for (int r=0;r<4;r++) {
          float p = __expf(s[ip][jt][r]*inv_s + mj - cvals[ip][r]);
          lrun[ip][r] += p;
          sP[wiq*32 + ip*16 + quad*4 + r][wjq*32 + jt*16 + col] = f16_bits(p);
        }
    }

    __syncthreads();                  // B: sP visible; QK reads of sQ done
    if (ji + 1 < 32) stage_Q(j0+128); // overlaps PV, drained at next barrier A

    // ---- PV: O[64 i x 32 c] for this wave's c-slab, K=128 (unchanged from R2)
    half8 bF23[2][2];
    #pragma unroll
    for (int ks2=0;ks2<2;ks2++)
      #pragma unroll
      for (int ct=0;ct<2;ct++) {
        int c = w*32 + ct*16 + col;
        bF23[ks2][ct] = ld_half8(f_n + (size_t)c*HWX + j0 + (ks2+2)*32 + quad*8);
      }
    __builtin_amdgcn_s_setprio(1);
    #pragma unroll
    for (int ks2=0; ks2<4; ks2++) {
      half8 aP[4];
      #pragma unroll
      for (int ig=0;ig<4;ig++) {
        const unsigned short* pp = &sP[ig*16 + col][ks2*32 + quad*8];
        s16x4 lo = *(const s16x4*)pp;        // rows 8B-aligned (264B stride)
        s16x4 hi = *(const s16x4*)(pp + 4);
        short8 vv = __builtin_shufflevector(lo, hi, 0,1,2,3,4,5,6,7);
        aP[ig] = __builtin_bit_cast(half8, vv);
      }
      #pragma unroll
      for (int ct=0;ct<2;ct++) {
        half8 bF = (ks2 < 2) ? bF01[ks2][ct] : bF23[ks2-2][ct];
        #pragma unroll
        for (int ig=0;ig<4;ig++)
          o[ig][ct] = __builtin_amdgcn_mfma_f32_16x16x32_f16(aP[ig], bF, o[ig][ct], 0, 0, 0);
      }
    }
    __builtin_amdgcn_s_setprio(0);
  }

  // ---- final l: reduce 16 j-cols in-wave (per j-quarter), combine 4 quarters via LDS
  #pragma unroll
  for (int ip=0;ip<2;ip++)
    #pragma unroll
    for (int r=0;r<4;r++) {
      float ss = lrun[ip][r];
      ss += __shfl_xor(ss, 1, 64);
      ss += __shfl_xor(ss, 2, 64);
      ss += __shfl_xor(ss, 4, 64);
      ss += __shfl_xor(ss, 8, 64);
      if (col == 0) sL[wjq][wiq*32 + ip*16 + quad*4 + r] = ss;
    }
  __syncthreads();
  #pragma unroll
  for (int ig=0;ig<4;ig++) {
    int base = ig*16 + quad*4;
    f32x4 l0 = *(const f32x4*)&sL[0][base];
    f32x4 l1 = *(const f32x4*)&sL[1][base];
    f32x4 l2 = *(const f32x4*)&sL[2][base];
    f32x4 l3 = *(const f32x4*)&sL[3][base];
    f32x4 mv = *(const f32x4*)(m_n + i0 + base);
    f32x4 minv;
    #pragma unroll
    for (int r=0;r<4;r++) minv[r] = mv[r] / (l0[r] + l1[r] + l2[r] + l3[r]);
    #pragma unroll
    for (int ct=0;ct<2;ct++) {
      int c = w*32 + ct*16 + col;
      f32x4 v;
      #pragma unroll
      for (int r=0;r<4;r++) v[r] = o[ig][ct][r] * minv[r];
      *(f32x4*)(out + ((size_t)n*CF + c)*HWX + i0 + base) = v;
    }
  }
}

extern "C" void kernel_launch(void* const* d_in, const int* in_sizes, int n_in,
                              void* d_out, int out_size, void* d_ws, size_t ws_size,
                              hipStream_t stream) {
  const float* x    = (const float*)d_in[0];
  const float* mask = (const float*)d_in[1];
  const float* rw   = (const float*)d_in[2];
  const float* rg   = (const float*)d_in[3];
  const float* rb   = (const float*)d_in[4];
  const float* rm   = (const float*)d_in[5];
  const float* rv   = (const float*)d_in[6];
  const float* aw   = (const float*)d_in[7];
  const float* ag   = (const float*)d_in[8];
  const float* ab   = (const float*)d_in[9];
  const float* am   = (const float*)d_in[10];
  const float* av   = (const float*)d_in[11];
  float* out = (float*)d_out;
  char* ws = (char*)d_ws;
  unsigned short* wh = (unsigned short*)(ws + OFF_WH);
  float* bias = (float*)(ws + OFF_BIAS);
  unsigned short* feat = (unsigned short*)(ws + OFF_FEAT);
  unsigned short* q    = (unsigned short*)(ws + OFF_Q);
  float* normq = (float*)(ws + OFF_NORM);
  unsigned* Gmax = (unsigned*)(ws + OFF_G);

  hipLaunchKernelGGL(fold_bn_k, dim3(CT), dim3(CIN), 0, stream,
                     rw, rg, rb, rm, rv, aw, ag, ab, am, av, wh, bias, Gmax);
  hipLaunchKernelGGL(conv_k, dim3(512), dim3(512), 0, stream,
                     x, wh, bias, feat, q, normq, Gmax);
  hipLaunchKernelGGL(flash_k, dim3(512), dim3(512), 0, stream,
                     q, feat, mask, normq, Gmax, out);
}

// Round 9
// 305.260 us; speedup vs baseline: 2.1942x; 1.2757x over previous
//
#include <hip/hip_runtime.h>
#include <cstdint>
#include <cstddef>

#define NB 8
#define CIN 256
#define HWX 4096
#define CF 256
#define CA 128
#define CT 384

typedef __attribute__((ext_vector_type(8))) _Float16 half8;
typedef __attribute__((ext_vector_type(8))) short short8;
typedef __attribute__((ext_vector_type(4))) short s16x4;
typedef __attribute__((ext_vector_type(4))) float f32x4;
typedef __attribute__((ext_vector_type(4))) unsigned int u32x4;
typedef __attribute__((ext_vector_type(2))) unsigned int u32x2;

// workspace layout (bytes)
#define OFF_WH   0                              // 384*256 fp16 folded weights
#define OFF_BIAS (CT*CIN*2)                     // 384 fp32 folded bias
#define OFF_FEAT (OFF_BIAS + CT*4)              // [n][256][4096] fp16
#define OFF_Q    (OFF_FEAT + NB*CF*HWX*2)       // [n][4096][128] fp16
#define OFF_NORM (OFF_Q + NB*HWX*CA*2)          // [n][4096] fp32 row norms of q
#define OFF_G    (OFF_NORM + NB*HWX*4)          // [n] uint (max norm bits)

__device__ inline unsigned short f16_bits(float f) {
  _Float16 h = (_Float16)f;
  return __builtin_bit_cast(unsigned short, h);
}
__device__ inline half8 ld_half8(const unsigned short* p) {
  short8 r = *(const short8*)p;
  return __builtin_bit_cast(half8, r);
}

// async global->LDS, 16B per lane; LDS side must be lane-linear (m104/m108),
// swizzle goes on the GLOBAL address.
__device__ inline void g2l16(const void* g, void* l) {
  __builtin_amdgcn_global_load_lds(
      (const __attribute__((address_space(1))) unsigned int*)g,
      (__attribute__((address_space(3))) unsigned int*)l, 16, 0, 0);
}

// ---------------- kernel 1: fold BN into fp16 weights (+ zero G) ----------------
__global__ __launch_bounds__(256) void fold_bn_k(
    const float* __restrict__ rw, const float* __restrict__ rg,
    const float* __restrict__ rb, const float* __restrict__ rm, const float* __restrict__ rv,
    const float* __restrict__ aw, const float* __restrict__ ag,
    const float* __restrict__ ab2, const float* __restrict__ am, const float* __restrict__ av,
    unsigned short* __restrict__ wh, float* __restrict__ bias, unsigned* __restrict__ Gmax) {
  int o = blockIdx.x, k = threadIdx.x;
  if (o == 0 && k < NB) Gmax[k] = 0u;
  const float* wsrc; float g, b, m, v;
  if (o < CF) { wsrc = rw + (size_t)o*CIN; g = rg[o]; b = rb[o]; m = rm[o]; v = rv[o]; }
  else { int oa = o - CF; wsrc = aw + (size_t)oa*CIN; g = ag[oa]; b = ab2[oa]; m = am[oa]; v = av[oa]; }
  float inv = g / sqrtf(v + 1e-5f);
  wh[(size_t)o*CIN + k] = f16_bits(wsrc[k] * inv);
  if (k == 0) bias[o] = b - m*inv;
}

// ---------------- kernel 2: fp16 MFMA conv(1x1)+BN+ReLU ----------------
// grid 512 = 8n x 64 pos-tiles(64); 512 thr (8 waves); 2 blocks/CU.
// Block tile: [64 pos] x [384 oc] x K=256. Wave w owns oc slab [w*48, w*48+48).
// B3 weight frags register-prefetched one ks ahead (R3); Gmax 1 atomic/block (R6).
// Both kept: conv residual fell 111 -> 93us with these.
__global__ __launch_bounds__(512, 4) void conv_k(
    const float* __restrict__ x, const unsigned short* __restrict__ wh,
    const float* __restrict__ bias, unsigned short* __restrict__ feat,
    unsigned short* __restrict__ q, float* __restrict__ normq,
    unsigned* __restrict__ Gmax) {
  __shared__ unsigned short sX[64*256];   // xT [64 pos][256 k] fp16, swizzled; 32KB
  __shared__ float sGm[4];
  unsigned short (*sQr)[136] = (unsigned short(*)[136])sX;  // aliased after K-loop
  int b = blockIdx.x;
  int n = b & 7, pt0 = b >> 3;
  int p0 = pt0 * 64;
  int t = threadIdx.x;
  int w = t >> 6, lane = t & 63, quad = lane >> 4, col = lane & 15;
  const float* xn = x + (size_t)n*CIN*HWX;

  // stage x tile [256 k][64 pos] -> sX transposed fp16, swizzled.
  #pragma unroll
  for (int pass=0; pass<4; pass++) {
    int idx = pass*512 + t;
    int kp = idx >> 4, c4 = idx & 15;
    f32x4 a = *(const f32x4*)(xn + (size_t)(2*kp)*HWX + p0 + c4*4);
    f32x4 c = *(const f32x4*)(xn + (size_t)(2*kp+1)*HWX + p0 + c4*4);
    int unit = kp >> 2, off = kp & 3;
    #pragma unroll
    for (int j=0;j<4;j++) {
      int pos = c4*4 + j;
      unsigned dd = (unsigned)f16_bits(a[j]) | ((unsigned)f16_bits(c[j]) << 16);
      *(unsigned*)&sX[pos*256 + ((unit ^ (pos & 31)) << 3) + off*2] = dd;
    }
  }
  __syncthreads();

  f32x4 fzero = {0.f,0.f,0.f,0.f};
  f32x4 acc[4][3];                  // [pos-tile][oc-tile]
  #pragma unroll
  for (int pt=0;pt<4;pt++)
    #pragma unroll
    for (int ot=0;ot<3;ot++) acc[pt][ot] = fzero;

  int ocb = w*48;
  half8 B3[3];
  #pragma unroll
  for (int ot=0;ot<3;ot++)
    B3[ot] = ld_half8(wh + (size_t)(ocb + ot*16 + col)*CIN + quad*8);   // ks=0
  #pragma unroll
  for (int ks=0; ks<8; ks++) {
    half8 B3n[3];
    if (ks < 7) {
      #pragma unroll
      for (int ot=0;ot<3;ot++)
        B3n[ot] = ld_half8(wh + (size_t)(ocb + ot*16 + col)*CIN + (ks+1)*32 + quad*8);
    }
    half8 A4[4];
    #pragma unroll
    for (int pt=0;pt<4;pt++) {
      int pos = pt*16 + col;
      A4[pt] = ld_half8(&sX[pos*256 + (((ks*4 + quad) ^ (pos & 31)) << 3)]);
    }
    #pragma unroll
    for (int pt=0;pt<4;pt++)
      #pragma unroll
      for (int ot=0;ot<3;ot++)
        acc[pt][ot] = __builtin_amdgcn_mfma_f32_16x16x32_f16(A4[pt], B3[ot], acc[pt][ot], 0, 0, 0);
    if (ks < 7) {
      #pragma unroll
      for (int ot=0;ot<3;ot++) B3[ot] = B3n[ot];
    }
  }
  __syncthreads();   // all sX reads done; region reused as sQr

  // epilogue: bias+ReLU; feat (oc<256) direct 8B stores; q (oc>=256) via LDS transpose
  float bv[3];
  #pragma unroll
  for (int ot=0;ot<3;ot++) bv[ot] = bias[ocb + ot*16 + col];
  #pragma unroll
  for (int pt=0;pt<4;pt++)
    #pragma unroll
    for (int ot=0;ot<3;ot++) {
      int oc = ocb + ot*16 + col;
      alignas(8) unsigned short u4[4];
      #pragma unroll
      for (int r=0;r<4;r++)
        u4[r] = f16_bits(fmaxf(acc[pt][ot][r] + bv[ot], 0.f));
      if (oc < CF) {
        *(u32x2*)(feat + (size_t)n*CF*HWX + (size_t)oc*HWX + p0 + pt*16 + quad*4) =
            *(const u32x2*)u4;
      } else {
        int cc = oc - CF;
        #pragma unroll
        for (int r=0;r<4;r++)
          sQr[pt*16 + quad*4 + r][cc] = u4[r];
      }
    }
  __syncthreads();

  // q readback + row norms: t<256: pos = t>>2 (64), seg = t&3 (32 c each)
  if (t < 256) {
    int pos = t >> 2, seg = t & 3;
    const unsigned short* src = &sQr[pos][seg*32];
    unsigned short* dst = q + ((size_t)n*HWX + p0 + pos)*CA + seg*32;
    float s2 = 0.f;
    #pragma unroll
    for (int u=0;u<4;u++) {
      short8 v = *(const short8*)(src + u*8);
      *(short8*)(dst + u*8) = v;
      half8 h = __builtin_bit_cast(half8, v);
      #pragma unroll
      for (int e=0;e<8;e++) { float fe = (float)h[e]; s2 += fe*fe; }
    }
    s2 += __shfl_xor(s2, 1, 64);
    s2 += __shfl_xor(s2, 2, 64);
    if (seg == 0) normq[(size_t)n*HWX + p0 + pos] = sqrtf(s2);
    float mx = s2;
    mx = fmaxf(mx, __shfl_xor(mx, 4, 64));
    mx = fmaxf(mx, __shfl_xor(mx, 8, 64));
    mx = fmaxf(mx, __shfl_xor(mx, 16, 64));
    mx = fmaxf(mx, __shfl_xor(mx, 32, 64));
    if (lane == 0) sGm[t >> 6] = sqrtf(mx);
  }
  __syncthreads();
  if (t == 0) {
    float m01 = fmaxf(sGm[0], sGm[1]);
    float m23 = fmaxf(sGm[2], sGm[3]);
    atomicMax(Gmax + n, __float_as_uint(fmaxf(m01, m23)));
  }
}

// ---------------- kernel 3: flash attention, BN=64, dbuf, ONE barrier/iter ----------------
// grid 512 = 8n x 64 i-tiles (BM=64); 512 thr (8 waves), 2 blocks/CU.
// R8: same algorithm as R7 (j-tile 64, full double-buffer, single barrier/iter) but
// with COMPILE-TIME buffer selection: named sQ0/sQ1, sP0/sP1, sM0/sM1 and a 2x
// unrolled loop body (even iter -> buf0, odd -> buf1). Eliminates runtime-indexed
// LDS bases for global_load_lds destinations (the only novel codegen pattern vs all
// previously-passing rounds; suspected in the 4 consecutive container failures).
// Hazard proof per R7: stage(ji+1)->bufB after BAR(ji-1) whose last reader QK(ji-1)
// precedes that barrier; g2l16 drained by BAR(ji)'s implicit vmcnt(0) before QK(ji+1);
// softmax(ji) writes sP_cur whose last reader PV(ji-2) is separated by BAR(ji-1).
// 64 iters x 1 barrier == R2's 32 x 2, but the drift window now spans
// PV(ji)+stage+QK(ji+1)+softmax(ji+1): lagging waves' PV-MFMA overlaps leading
// waves' softmax-VALU within a block (R2 lock-step forbade that; MfmaUtil pinned
// 24% with conflicts=0, HBM 4%). Register budget: K=64 halves bF to 16 regs; live
// set ~100 < R2's proven ~116 << 128 cap (guard: FETCH must stay ~17-25MB).
// Bank patterns: pad 68 == pad 132 mod-32 classes (P-store quads at +8 banks,
// conflict-free measured R1/R2; aP 8B reads 2-way == free per m136).
__global__ __launch_bounds__(512, 4) void flash_k(
    const unsigned short* __restrict__ q, const unsigned short* __restrict__ feat,
    const float* __restrict__ mask, const float* __restrict__ normq,
    const unsigned* __restrict__ Gmax, float* __restrict__ out) {
  __shared__ alignas(16) unsigned short sQ0[64*128];  // j-tile q fp16, octet-swizzled
  __shared__ alignas(16) unsigned short sQ1[64*128];
  __shared__ alignas(16) unsigned short sP0[64][68];  // P (A-layout), pad 68
  __shared__ alignas(16) unsigned short sP1[64][68];
  __shared__ float sM0[64];
  __shared__ float sM1[64];
  __shared__ float sL[2][64];
  int b = blockIdx.x;
  int n = b & 7, it = b >> 3;         // n == XCD for L2 locality
  int i0 = it * 64;
  int t = threadIdx.x;
  int w = t >> 6, lane = t & 63, quad = lane >> 4, col = lane & 15;
  int wq = w & 3, wh = w >> 2;        // QK: wq = i-16-block, wh = j-32-half
  const unsigned short* q_n = q + (size_t)n*HWX*CA;
  const unsigned short* f_n = feat + (size_t)n*CF*HWX;
  const float* m_n = mask + (size_t)n*HWX;
  const int rloc = t >> 4 & 31, oct16 = t & 15;
  const float inv_s = 1.0f/(1e-8f + sqrtf(128.0f));

  auto stage_Q = [&](int j0, unsigned short* sQd, float* sMd) {
    #pragma unroll
    for (int c=0;c<2;c++) {
      int row = c*32 + rloc;
      int og = oct16 ^ (row & 15);
      g2l16(q_n + (size_t)(j0+row)*CA + og*8, &sQd[(size_t)row*128 + oct16*8]);
    }
    if (t < 16) g2l16(m_n + j0 + t*4, &sMd[t*4]);
  };

  // A fragments for QK (this wave's 16 i rows), resident all iters
  half8 ah[4];
  {
    int arow = i0 + wq*16 + col;
    #pragma unroll
    for (int ks=0; ks<4; ks++)
      ah[ks] = ld_half8(q_n + (size_t)arow*CA + ks*32 + quad*8);
  }
  // per-row exp shift: C_i - 5 (max-free softmax via Cauchy-Schwarz bound)
  float Gn = __uint_as_float(Gmax[n]);
  float cvals[4];
  #pragma unroll
  for (int r=0;r<4;r++)
    cvals[r] = normq[(size_t)n*HWX + i0 + wq*16 + quad*4 + r] * Gn * inv_s - 5.0f;

  f32x4 fzero = {0.f,0.f,0.f,0.f};
  f32x4 o[4][2];                      // [i-group][c-tile], PV c-slab = w*32
  #pragma unroll
  for (int ig=0;ig<4;ig++) { o[ig][0] = fzero; o[ig][1] = fzero; }
  float lrun[4] = {0.f,0.f,0.f,0.f};

  // one iteration; all LDS bases are compile-time-constant at each call site
  auto iter = [&](int ji, unsigned short* sQc, unsigned short (*sPc)[68], float* sMc,
                  unsigned short* sQn, float* sMn) {
    int j0 = ji*64;

    // ---- phase 1: issue next stage (drains at this iter's barrier)
    if (ji + 1 < 64) stage_Q(j0+64, sQn, sMn);

    // prefetch PV B-frags (K=64); consumed post-barrier, latency hides under QK+SM
    half8 bF[2][2];
    #pragma unroll
    for (int ks2=0;ks2<2;ks2++)
      #pragma unroll
      for (int ct=0;ct<2;ct++) {
        int c = w*32 + ct*16 + col;
        bF[ks2][ct] = ld_half8(f_n + (size_t)c*HWX + j0 + ks2*32 + quad*8);
      }

    // ---- QK^T: S[16 i x 32 j] (this wave's j-half), 2 indep chains of 4
    f32x4 s[2];
    s[0] = fzero; s[1] = fzero;
    __builtin_amdgcn_s_setprio(1);
    #pragma unroll
    for (int jt=0;jt<2;jt++) {
      int rowj = wh*32 + jt*16 + col;
      #pragma unroll
      for (int ks=0; ks<4; ks++) {
        int slot = (ks*4 + quad) ^ (rowj & 15);
        half8 bq = ld_half8(&sQc[rowj*128 + slot*8]);
        s[jt] = __builtin_amdgcn_mfma_f32_16x16x32_f16(ah[ks], bq, s[jt], 0, 0, 0);
      }
    }
    __builtin_amdgcn_s_setprio(0);

    // ---- max-free softmax: P = exp(E*inv_s + maskterm - C_i + 5); l += P
    #pragma unroll
    for (int jt=0;jt<2;jt++) {
      float mj = (sMc[wh*32 + jt*16 + col] - 1.f) * 1e8f;
      #pragma unroll
      for (int r=0;r<4;r++) {
        float pv = __expf(s[jt][r]*inv_s + mj - cvals[r]);
        lrun[r] += pv;
        sPc[wq*16 + quad*4 + r][wh*32 + jt*16 + col] = f16_bits(pv);
      }
    }

    __syncthreads();   // THE barrier: sPc + next sQ visible; QK reads done

    // ---- phase 2: PV: O[64 i x 32 c] for this wave's c-slab, K=64
    __builtin_amdgcn_s_setprio(1);
    #pragma unroll
    for (int ks2=0; ks2<2; ks2++) {
      half8 aP[4];
      #pragma unroll
      for (int ig=0;ig<4;ig++) {
        const unsigned short* pp = &sPc[ig*16 + col][ks2*32 + quad*8];
        s16x4 lo = *(const s16x4*)pp;        // rows 8B-aligned (136B stride)
        s16x4 hi = *(const s16x4*)(pp + 4);
        short8 vv = __builtin_shufflevector(lo, hi, 0,1,2,3,4,5,6,7);
        aP[ig] = __builtin_bit_cast(half8, vv);
      }
      #pragma unroll
      for (int ct=0;ct<2;ct++) {
        #pragma unroll
        for (int ig=0;ig<4;ig++)
          o[ig][ct] = __builtin_amdgcn_mfma_f32_16x16x32_f16(aP[ig], bF[ks2][ct], o[ig][ct], 0, 0, 0);
      }
    }
    __builtin_amdgcn_s_setprio(0);
  };

  stage_Q(0, sQ0, sM0);
  __syncthreads();                    // drain initial stage
  #pragma unroll 1
  for (int jj = 0; jj < 32; jj++) {
    iter(2*jj,     sQ0, sP0, sM0, sQ1, sM1);   // even: buf0, stages buf1
    iter(2*jj + 1, sQ1, sP1, sM1, sQ0, sM0);   // odd:  buf1, stages buf0
  }

  // ---- final l: reduce 16 j-cols in-wave, combine the 2 j-halves via LDS
  #pragma unroll
  for (int r=0;r<4;r++) {
    float ss = lrun[r];
    ss += __shfl_xor(ss, 1, 64);
    ss += __shfl_xor(ss, 2, 64);
    ss += __shfl_xor(ss, 4, 64);
    ss += __shfl_xor(ss, 8, 64);
    lrun[r] = ss;
  }
  #pragma unroll
  for (int r=0;r<4;r++)
    if (col == 0) sL[wh][wq*16 + quad*4 + r] = lrun[r];
  __syncthreads();
  #pragma unroll
  for (int ig=0;ig<4;ig++) {
    int base = ig*16 + quad*4;
    f32x4 l0 = *(const f32x4*)&sL[0][base];
    f32x4 l1 = *(const f32x4*)&sL[1][base];
    f32x4 mv = *(const f32x4*)(m_n + i0 + base);
    f32x4 minv;
    #pragma unroll
    for (int r=0;r<4;r++) minv[r] = mv[r] / (l0[r] + l1[r]);
    #pragma unroll
    for (int ct=0;ct<2;ct++) {
      int c = w*32 + ct*16 + col;
      f32x4 v;
      #pragma unroll
      for (int r=0;r<4;r++) v[r] = o[ig][ct][r] * minv[r];
      *(f32x4*)(out + ((size_t)n*CF + c)*HWX + i0 + base) = v;
    }
  }
}

extern "C" void kernel_launch(void* const* d_in, const int* in_sizes, int n_in,
                              void* d_out, int out_size, void* d_ws, size_t ws_size,
                              hipStream_t stream) {
  const float* x    = (const float*)d_in[0];
  const float* mask = (const float*)d_in[1];
  const float* rw   = (const float*)d_in[2];
  const float* rg   = (const float*)d_in[3];
  const float* rb   = (const float*)d_in[4];
  const float* rm   = (const float*)d_in[5];
  const float* rv   = (const float*)d_in[6];
  const float* aw   = (const float*)d_in[7];
  const float* ag   = (const float*)d_in[8];
  const float* ab   = (const float*)d_in[9];
  const float* am   = (const float*)d_in[10];
  const float* av   = (const float*)d_in[11];
  float* out = (float*)d_out;
  char* ws = (char*)d_ws;
  unsigned short* wh = (unsigned short*)(ws + OFF_WH);
  float* bias = (float*)(ws + OFF_BIAS);
  unsigned short* feat = (unsigned short*)(ws + OFF_FEAT);
  unsigned short* q    = (unsigned short*)(ws + OFF_Q);
  float* normq = (float*)(ws + OFF_NORM);
  unsigned* Gmax = (unsigned*)(ws + OFF_G);

  hipLaunchKernelGGL(fold_bn_k, dim3(CT), dim3(CIN), 0, stream,
                     rw, rg, rb, rm, rv, aw, ag, ab, am, av, wh, bias, Gmax);
  hipLaunchKernelGGL(conv_k, dim3(512), dim3(512), 0, stream,
                     x, wh, bias, feat, q, normq, Gmax);
  hipLaunchKernelGGL(flash_k, dim3(512), dim3(512), 0, stream,
                     q, feat, mask, normq, Gmax, out);
}

// Round 10
// 290.067 us; speedup vs baseline: 2.3091x; 1.0524x over previous
//
#include <hip/hip_runtime.h>
#include <cstdint>
#include <cstddef>

#define NB 8
#define CIN 256
#define HWX 4096
#define CF 256
#define CA 128
#define CT 384

typedef __attribute__((ext_vector_type(8))) _Float16 half8;
typedef __attribute__((ext_vector_type(8))) short short8;
typedef __attribute__((ext_vector_type(4))) short s16x4;
typedef __attribute__((ext_vector_type(4))) float f32x4;
typedef __attribute__((ext_vector_type(4))) unsigned int u32x4;
typedef __attribute__((ext_vector_type(2))) unsigned int u32x2;

// workspace layout (bytes)
#define OFF_WH   0                              // 384*256 fp16 folded weights
#define OFF_BIAS (CT*CIN*2)                     // 384 fp32 folded bias
#define OFF_FEAT (OFF_BIAS + CT*4)              // [n][256][4096] fp16
#define OFF_Q    (OFF_FEAT + NB*CF*HWX*2)       // [n][4096][128] fp16
#define OFF_NORM (OFF_Q + NB*HWX*CA*2)          // [n][4096] fp32 row norms of q
#define OFF_G    (OFF_NORM + NB*HWX*4)          // [n] uint (max norm bits)

__device__ inline unsigned short f16_bits(float f) {
  _Float16 h = (_Float16)f;
  return __builtin_bit_cast(unsigned short, h);
}
__device__ inline half8 ld_half8(const unsigned short* p) {
  short8 r = *(const short8*)p;
  return __builtin_bit_cast(half8, r);
}

// async global->LDS, 16B per lane; LDS side must be lane-linear (m104/m108),
// swizzle goes on the GLOBAL address.
__device__ inline void g2l16(const void* g, void* l) {
  __builtin_amdgcn_global_load_lds(
      (const __attribute__((address_space(1))) unsigned int*)g,
      (__attribute__((address_space(3))) unsigned int*)l, 16, 0, 0);
}

// ---------------- kernel 1: fold BN into fp16 weights (+ zero G) ----------------
__global__ __launch_bounds__(256) void fold_bn_k(
    const float* __restrict__ rw, const float* __restrict__ rg,
    const float* __restrict__ rb, const float* __restrict__ rm, const float* __restrict__ rv,
    const float* __restrict__ aw, const float* __restrict__ ag,
    const float* __restrict__ ab2, const float* __restrict__ am, const float* __restrict__ av,
    unsigned short* __restrict__ wh, float* __restrict__ bias, unsigned* __restrict__ Gmax) {
  int o = blockIdx.x, k = threadIdx.x;
  if (o == 0 && k < NB) Gmax[k] = 0u;
  const float* wsrc; float g, b, m, v;
  if (o < CF) { wsrc = rw + (size_t)o*CIN; g = rg[o]; b = rb[o]; m = rm[o]; v = rv[o]; }
  else { int oa = o - CF; wsrc = aw + (size_t)oa*CIN; g = ag[oa]; b = ab2[oa]; m = am[oa]; v = av[oa]; }
  float inv = g / sqrtf(v + 1e-5f);
  wh[(size_t)o*CIN + k] = f16_bits(wsrc[k] * inv);
  if (k == 0) bias[o] = b - m*inv;
}

// ---------------- kernel 2: fp16 MFMA conv(1x1)+BN+ReLU, 32-pos tiles ----------------
// R10: pos-tile 64 -> 32. grid 1024 = 8n x 128 pos-tiles(32); 512 thr (8 waves).
// LDS 32KB -> 16KB, acc 48 -> 24 VGPR (live ~72 <= 85 cap at launch_bounds(512,6))
// -> 3 blocks/CU (was grid-capped at 2) and 2x independent barrier groups: conv was
// the one kernel still lock-stepped at 2 groups/CU. Roofline says conv should be
// ~15us (6.4 GFLOP, ~60MB); residual ~93-98us and it responded to both prior
// latency fixes (B3 prefetch R3, single atomic R6: 111 -> 93) -- same serialization
// disease flash had. Same staging swizzle (k-pair/unit math unchanged), B3 register
// prefetch kept, 1 atomic/block kept.
__global__ __launch_bounds__(512, 6) void conv_k(
    const float* __restrict__ x, const unsigned short* __restrict__ wh,
    const float* __restrict__ bias, unsigned short* __restrict__ feat,
    unsigned short* __restrict__ q, float* __restrict__ normq,
    unsigned* __restrict__ Gmax) {
  __shared__ unsigned short sX[32*256];   // xT [32 pos][256 k] fp16, swizzled; 16KB
  __shared__ float sGm[2];
  unsigned short (*sQr)[136] = (unsigned short(*)[136])sX;  // aliased after K-loop
  int b = blockIdx.x;
  int n = b & 7, pt0 = b >> 3;
  int p0 = pt0 * 32;
  int t = threadIdx.x;
  int w = t >> 6, lane = t & 63, quad = lane >> 4, col = lane & 15;
  const float* xn = x + (size_t)n*CIN*HWX;

  // stage x tile [256 k][32 pos] -> sX transposed fp16, swizzled. 2 passes.
  #pragma unroll
  for (int pass=0; pass<2; pass++) {
    int idx = pass*512 + t;
    int kp = idx >> 3, c4 = idx & 7;      // 128 k-pairs x 8 f32x4 pos-groups
    f32x4 a = *(const f32x4*)(xn + (size_t)(2*kp)*HWX + p0 + c4*4);
    f32x4 c = *(const f32x4*)(xn + (size_t)(2*kp+1)*HWX + p0 + c4*4);
    int unit = kp >> 2, off = kp & 3;
    #pragma unroll
    for (int j=0;j<4;j++) {
      int pos = c4*4 + j;
      unsigned dd = (unsigned)f16_bits(a[j]) | ((unsigned)f16_bits(c[j]) << 16);
      *(unsigned*)&sX[pos*256 + ((unit ^ (pos & 31)) << 3) + off*2] = dd;
    }
  }
  __syncthreads();

  f32x4 fzero = {0.f,0.f,0.f,0.f};
  f32x4 acc[2][3];                  // [pos-tile][oc-tile]
  #pragma unroll
  for (int pt=0;pt<2;pt++)
    #pragma unroll
    for (int ot=0;ot<3;ot++) acc[pt][ot] = fzero;

  int ocb = w*48;
  half8 B3[3];
  #pragma unroll
  for (int ot=0;ot<3;ot++)
    B3[ot] = ld_half8(wh + (size_t)(ocb + ot*16 + col)*CIN + quad*8);   // ks=0
  #pragma unroll
  for (int ks=0; ks<8; ks++) {
    half8 B3n[3];
    if (ks < 7) {
      #pragma unroll
      for (int ot=0;ot<3;ot++)
        B3n[ot] = ld_half8(wh + (size_t)(ocb + ot*16 + col)*CIN + (ks+1)*32 + quad*8);
    }
    half8 A4[2];
    #pragma unroll
    for (int pt=0;pt<2;pt++) {
      int pos = pt*16 + col;
      A4[pt] = ld_half8(&sX[pos*256 + (((ks*4 + quad) ^ (pos & 31)) << 3)]);
    }
    #pragma unroll
    for (int pt=0;pt<2;pt++)
      #pragma unroll
      for (int ot=0;ot<3;ot++)
        acc[pt][ot] = __builtin_amdgcn_mfma_f32_16x16x32_f16(A4[pt], B3[ot], acc[pt][ot], 0, 0, 0);
    if (ks < 7) {
      #pragma unroll
      for (int ot=0;ot<3;ot++) B3[ot] = B3n[ot];
    }
  }
  __syncthreads();   // all sX reads done; region reused as sQr

  // epilogue: bias+ReLU; feat (oc<256) direct 8B stores; q (oc>=256) via LDS transpose
  float bv[3];
  #pragma unroll
  for (int ot=0;ot<3;ot++) bv[ot] = bias[ocb + ot*16 + col];
  #pragma unroll
  for (int pt=0;pt<2;pt++)
    #pragma unroll
    for (int ot=0;ot<3;ot++) {
      int oc = ocb + ot*16 + col;
      alignas(8) unsigned short u4[4];
      #pragma unroll
      for (int r=0;r<4;r++)
        u4[r] = f16_bits(fmaxf(acc[pt][ot][r] + bv[ot], 0.f));
      if (oc < CF) {
        *(u32x2*)(feat + (size_t)n*CF*HWX + (size_t)oc*HWX + p0 + pt*16 + quad*4) =
            *(const u32x2*)u4;
      } else {
        int cc = oc - CF;
        #pragma unroll
        for (int r=0;r<4;r++)
          sQr[pt*16 + quad*4 + r][cc] = u4[r];
      }
    }
  __syncthreads();

  // q readback + row norms: t<128: pos = t>>2 (32), seg = t&3 (32 c each)
  if (t < 128) {
    int pos = t >> 2, seg = t & 3;
    const unsigned short* src = &sQr[pos][seg*32];
    unsigned short* dst = q + ((size_t)n*HWX + p0 + pos)*CA + seg*32;
    float s2 = 0.f;
    #pragma unroll
    for (int u=0;u<4;u++) {
      short8 v = *(const short8*)(src + u*8);
      *(short8*)(dst + u*8) = v;
      half8 h = __builtin_bit_cast(half8, v);
      #pragma unroll
      for (int e=0;e<8;e++) { float fe = (float)h[e]; s2 += fe*fe; }
    }
    s2 += __shfl_xor(s2, 1, 64);
    s2 += __shfl_xor(s2, 2, 64);
    if (seg == 0) normq[(size_t)n*HWX + p0 + pos] = sqrtf(s2);
    float mx = s2;
    mx = fmaxf(mx, __shfl_xor(mx, 4, 64));
    mx = fmaxf(mx, __shfl_xor(mx, 8, 64));
    mx = fmaxf(mx, __shfl_xor(mx, 16, 64));
    mx = fmaxf(mx, __shfl_xor(mx, 32, 64));
    if (lane == 0) sGm[t >> 6] = sqrtf(mx);   // waves 0,1 only
  }
  __syncthreads();
  if (t == 0)
    atomicMax(Gmax + n, __float_as_uint(fmaxf(sGm[0], sGm[1])));
}

// ---------------- kernel 3: flash attention, BN=128, two barriers/iter ----------------
// EXACT R2 kernel (measured 183us twice; every structural variant since was null or
// worse: R6 reg-cliff, R9 one-barrier dbuf -13%). g2l16 sQ pipeline = the latency
// hider (R1 proved direct-L2 QK collapses MfmaUtil 24->11). pad-132 sP: conflict-free
// verified (SQ_LDS_BANK_CONFLICT == 0). setprio kept (null but harmless).
__global__ __launch_bounds__(512, 4) void flash_k(
    const unsigned short* __restrict__ q, const unsigned short* __restrict__ feat,
    const float* __restrict__ mask, const float* __restrict__ normq,
    const unsigned* __restrict__ Gmax, float* __restrict__ out) {
  __shared__ alignas(16) unsigned short sQ[128*128];  // j-tile q fp16, octet-swizzled
  __shared__ alignas(16) unsigned short sP[64][132];  // P (A-layout), pad 132
  __shared__ float sM[128];
  __shared__ float sL[2][64];
  int b = blockIdx.x;
  int n = b & 7, it = b >> 3;         // n == XCD for L2 locality
  int i0 = it * 64;
  int t = threadIdx.x;
  int w = t >> 6, lane = t & 63, quad = lane >> 4, col = lane & 15;
  int wq = w & 3, wh = w >> 2;
  const unsigned short* q_n = q + (size_t)n*HWX*CA;
  const unsigned short* f_n = feat + (size_t)n*CF*HWX;
  const float* m_n = mask + (size_t)n*HWX;
  const int rloc = t >> 4 & 31, oct16 = t & 15;
  const float inv_s = 1.0f/(1e-8f + sqrtf(128.0f));

  auto stage_Q = [&](int j0) {
    #pragma unroll
    for (int c=0;c<4;c++) {
      int row = c*32 + rloc;
      int og = oct16 ^ (row & 15);
      g2l16(q_n + (size_t)(j0+row)*CA + og*8, &sQ[(size_t)row*128 + oct16*8]);
    }
    if (t < 32) g2l16(m_n + j0 + t*4, &sM[t*4]);
  };

  // A fragments for QK (this wave's 16 i rows)
  half8 ah[4];
  {
    int arow = i0 + wq*16 + col;
    #pragma unroll
    for (int ks=0; ks<4; ks++)
      ah[ks] = ld_half8(q_n + (size_t)arow*CA + ks*32 + quad*8);
  }
  // per-row exp shift: C_i - 5 (max-free softmax via Cauchy-Schwarz bound)
  float Gn = __uint_as_float(Gmax[n]);
  float cvals[4];
  #pragma unroll
  for (int r=0;r<4;r++)
    cvals[r] = normq[(size_t)n*HWX + i0 + wq*16 + quad*4 + r] * Gn * inv_s - 5.0f;

  f32x4 fzero = {0.f,0.f,0.f,0.f};
  f32x4 o[4][2];                      // [i-group][c-tile], c-slab = w*32
  #pragma unroll
  for (int ig=0;ig<4;ig++) { o[ig][0] = fzero; o[ig][1] = fzero; }
  float lrun[4] = {0.f,0.f,0.f,0.f};

  stage_Q(0);
  #pragma unroll 1
  for (int ji = 0; ji < 32; ji++) {
    int j0 = ji*128;
    __syncthreads();                  // A: sQ(ji)+sM(ji) ready; PV(ji-1) done with sP

    // prefetch PV B-frags for ks2=0,1 (consumed after barrier B; L2 latency hides
    // under QK+softmax). ks2=2,3 loaded at PV start to cap live registers.
    half8 bF01[2][2];
    #pragma unroll
    for (int ks2=0;ks2<2;ks2++)
      #pragma unroll
      for (int ct=0;ct<2;ct++) {
        int c = w*32 + ct*16 + col;
        bF01[ks2][ct] = ld_half8(f_n + (size_t)c*HWX + j0 + ks2*32 + quad*8);
      }

    // ---- QK^T: S[16 i x 64 j] (this wave's j-half), 4 indep chains of 4
    f32x4 s[4];
    #pragma unroll
    for (int jt=0;jt<4;jt++) s[jt] = fzero;
    __builtin_amdgcn_s_setprio(1);
    #pragma unroll
    for (int jt=0;jt<4;jt++) {
      int rowj = wh*64 + jt*16 + col;
      #pragma unroll
      for (int ks=0; ks<4; ks++) {
        int slot = (ks*4 + quad) ^ (rowj & 15);
        half8 bq = ld_half8(&sQ[rowj*128 + slot*8]);
        s[jt] = __builtin_amdgcn_mfma_f32_16x16x32_f16(ah[ks], bq, s[jt], 0, 0, 0);
      }
    }
    __builtin_amdgcn_s_setprio(0);

    // ---- max-free softmax: P = exp(E*inv_s + maskterm - C_i + 5); l += P
    // scalar b16 stores at stride 132 -> conflict-free (quads on banks 0/8/16/24)
    #pragma unroll
    for (int jt=0;jt<4;jt++) {
      float mj = (sM[wh*64 + jt*16 + col] - 1.f) * 1e8f;
      #pragma unroll
      for (int r=0;r<4;r++) {
        float p = __expf(s[jt][r]*inv_s + mj - cvals[r]);
        lrun[r] += p;
        sP[wq*16 + quad*4 + r][wh*64 + jt*16 + col] = f16_bits(p);
      }
    }

    __syncthreads();                  // B: sP visible; QK reads of sQ done
    if (ji + 1 < 32) stage_Q(j0+128); // overlaps PV, drained at next barrier A

    // ---- PV: O[64 i x 32 c] for this wave's c-slab, K=128
    half8 bF23[2][2];
    #pragma unroll
    for (int ks2=0;ks2<2;ks2++)
      #pragma unroll
      for (int ct=0;ct<2;ct++) {
        int c = w*32 + ct*16 + col;
        bF23[ks2][ct] = ld_half8(f_n + (size_t)c*HWX + j0 + (ks2+2)*32 + quad*8);
      }
    __builtin_amdgcn_s_setprio(1);
    #pragma unroll
    for (int ks2=0; ks2<4; ks2++) {
      half8 aP[4];
      #pragma unroll
      for (int ig=0;ig<4;ig++) {
        const unsigned short* pp = &sP[ig*16 + col][ks2*32 + quad*8];
        s16x4 lo = *(const s16x4*)pp;        // rows 8B-aligned (264B stride)
        s16x4 hi = *(const s16x4*)(pp + 4);
        short8 vv = __builtin_shufflevector(lo, hi, 0,1,2,3,4,5,6,7);
        aP[ig] = __builtin_bit_cast(half8, vv);
      }
      #pragma unroll
      for (int ct=0;ct<2;ct++) {
        half8 bF = (ks2 < 2) ? bF01[ks2][ct] : bF23[ks2-2][ct];
        #pragma unroll
        for (int ig=0;ig<4;ig++)
          o[ig][ct] = __builtin_amdgcn_mfma_f32_16x16x32_f16(aP[ig], bF, o[ig][ct], 0, 0, 0);
      }
    }
    __builtin_amdgcn_s_setprio(0);
  }

  // ---- final l: reduce 16 j-cols in-wave, combine halves via LDS
  #pragma unroll
  for (int r=0;r<4;r++) {
    float ss = lrun[r];
    ss += __shfl_xor(ss, 1, 64);
    ss += __shfl_xor(ss, 2, 64);
    ss += __shfl_xor(ss, 4, 64);
    ss += __shfl_xor(ss, 8, 64);
    lrun[r] = ss;
  }
  #pragma unroll
  for (int r=0;r<4;r++)
    if (col == 0) sL[wh][wq*16 + quad*4 + r] = lrun[r];
  __syncthreads();
  #pragma unroll
  for (int ig=0;ig<4;ig++) {
    int base = ig*16 + quad*4;
    f32x4 l0 = *(const f32x4*)&sL[0][base];
    f32x4 l1 = *(const f32x4*)&sL[1][base];
    f32x4 mv = *(const f32x4*)(m_n + i0 + base);
    f32x4 minv;
    #pragma unroll
    for (int r=0;r<4;r++) minv[r] = mv[r] / (l0[r] + l1[r]);
    #pragma unroll
    for (int ct=0;ct<2;ct++) {
      int c = w*32 + ct*16 + col;
      f32x4 v;
      #pragma unroll
      for (int r=0;r<4;r++) v[r] = o[ig][ct][r] * minv[r];
      *(f32x4*)(out + ((size_t)n*CF + c)*HWX + i0 + base) = v;
    }
  }
}

extern "C" void kernel_launch(void* const* d_in, const int* in_sizes, int n_in,
                              void* d_out, int out_size, void* d_ws, size_t ws_size,
                              hipStream_t stream) {
  const float* x    = (const float*)d_in[0];
  const float* mask = (const float*)d_in[1];
  const float* rw   = (const float*)d_in[2];
  const float* rg   = (const float*)d_in[3];
  const float* rb   = (const float*)d_in[4];
  const float* rm   = (const float*)d_in[5];
  const float* rv   = (const float*)d_in[6];
  const float* aw   = (const float*)d_in[7];
  const float* ag   = (const float*)d_in[8];
  const float* ab   = (const float*)d_in[9];
  const float* am   = (const float*)d_in[10];
  const float* av   = (const float*)d_in[11];
  float* out = (float*)d_out;
  char* ws = (char*)d_ws;
  unsigned short* wh = (unsigned short*)(ws + OFF_WH);
  float* bias = (float*)(ws + OFF_BIAS);
  unsigned short* feat = (unsigned short*)(ws + OFF_FEAT);
  unsigned short* q    = (unsigned short*)(ws + OFF_Q);
  float* normq = (float*)(ws + OFF_NORM);
  unsigned* Gmax = (unsigned*)(ws + OFF_G);

  hipLaunchKernelGGL(fold_bn_k, dim3(CT), dim3(CIN), 0, stream,
                     rw, rg, rb, rm, rv, aw, ag, ab, am, av, wh, bias, Gmax);
  hipLaunchKernelGGL(conv_k, dim3(1024), dim3(512), 0, stream,
                     x, wh, bias, feat, q, normq, Gmax);
  hipLaunchKernelGGL(flash_k, dim3(512), dim3(512), 0, stream,
                     q, feat, mask, normq, Gmax, out);
}

// Round 11
// 278.561 us; speedup vs baseline: 2.4045x; 1.0413x over previous
//
#include <hip/hip_runtime.h>
#include <cstdint>
#include <cstddef>

#define NB 8
#define CIN 256
#define HWX 4096
#define CF 256
#define CA 128
#define CT 384

typedef __attribute__((ext_vector_type(8))) _Float16 half8;
typedef __attribute__((ext_vector_type(8))) short short8;
typedef __attribute__((ext_vector_type(4))) short s16x4;
typedef __attribute__((ext_vector_type(4))) float f32x4;
typedef __attribute__((ext_vector_type(4))) unsigned int u32x4;
typedef __attribute__((ext_vector_type(2))) unsigned int u32x2;

// workspace layout (bytes)
#define OFF_WH   0                              // 384*256 fp16 folded weights
#define OFF_BIAS (CT*CIN*2)                     // 384 fp32 folded bias
#define OFF_FEAT (OFF_BIAS + CT*4)              // [n][256][4096] fp16
#define OFF_Q    (OFF_FEAT + NB*CF*HWX*2)       // [n][4096][128] fp16
#define OFF_NORM (OFF_Q + NB*HWX*CA*2)          // [n][4096] fp32 row norms of q
#define OFF_G    (OFF_NORM + NB*HWX*4)          // [n] uint (max norm bits)

__device__ inline unsigned short f16_bits(float f) {
  _Float16 h = (_Float16)f;
  return __builtin_bit_cast(unsigned short, h);
}
__device__ inline half8 ld_half8(const unsigned short* p) {
  short8 r = *(const short8*)p;
  return __builtin_bit_cast(half8, r);
}

// async global->LDS, 16B per lane; LDS side must be lane-linear (m104/m108),
// swizzle goes on the GLOBAL address.
__device__ inline void g2l16(const void* g, void* l) {
  __builtin_amdgcn_global_load_lds(
      (const __attribute__((address_space(1))) unsigned int*)g,
      (__attribute__((address_space(3))) unsigned int*)l, 16, 0, 0);
}

// ---------------- kernel 1: fold BN into fp16 weights (+ zero G) ----------------
__global__ __launch_bounds__(256) void fold_bn_k(
    const float* __restrict__ rw, const float* __restrict__ rg,
    const float* __restrict__ rb, const float* __restrict__ rm, const float* __restrict__ rv,
    const float* __restrict__ aw, const float* __restrict__ ag,
    const float* __restrict__ ab2, const float* __restrict__ am, const float* __restrict__ av,
    unsigned short* __restrict__ wh, float* __restrict__ bias, unsigned* __restrict__ Gmax) {
  int o = blockIdx.x, k = threadIdx.x;
  if (o == 0 && k < NB) Gmax[k] = 0u;
  const float* wsrc; float g, b, m, v;
  if (o < CF) { wsrc = rw + (size_t)o*CIN; g = rg[o]; b = rb[o]; m = rm[o]; v = rv[o]; }
  else { int oa = o - CF; wsrc = aw + (size_t)oa*CIN; g = ag[oa]; b = ab2[oa]; m = am[oa]; v = av[oa]; }
  float inv = g / sqrtf(v + 1e-5f);
  wh[(size_t)o*CIN + k] = f16_bits(wsrc[k] * inv);
  if (k == 0) bias[o] = b - m*inv;
}

// ---------------- kernel 2: fp16 MFMA conv(1x1)+BN+ReLU, 64-pos tiles ----------------
// EXACT R6 conv (best measured: residual 93-98us vs 105 for the R10 32-pos variant --
// halving the tile doubled per-block weight L2 traffic (192KB x 1024 blocks) and
// fixed costs, outweighing the occupancy gain). grid 512 = 8n x 64 pos-tiles(64);
// 512 thr (8 waves); 2 blocks/CU. Wave w owns oc slab [w*48, w*48+48).
// B3 register-prefetch one ks ahead (R3, real); 1 atomic/block (R6, real: 111->93).
__global__ __launch_bounds__(512, 4) void conv_k(
    const float* __restrict__ x, const unsigned short* __restrict__ wh,
    const float* __restrict__ bias, unsigned short* __restrict__ feat,
    unsigned short* __restrict__ q, float* __restrict__ normq,
    unsigned* __restrict__ Gmax) {
  __shared__ unsigned short sX[64*256];   // xT [64 pos][256 k] fp16, swizzled; 32KB
  __shared__ float sGm[4];
  unsigned short (*sQr)[136] = (unsigned short(*)[136])sX;  // aliased after K-loop
  int b = blockIdx.x;
  int n = b & 7, pt0 = b >> 3;
  int p0 = pt0 * 64;
  int t = threadIdx.x;
  int w = t >> 6, lane = t & 63, quad = lane >> 4, col = lane & 15;
  const float* xn = x + (size_t)n*CIN*HWX;

  // stage x tile [256 k][64 pos] -> sX transposed fp16, swizzled.
  #pragma unroll
  for (int pass=0; pass<4; pass++) {
    int idx = pass*512 + t;
    int kp = idx >> 4, c4 = idx & 15;
    f32x4 a = *(const f32x4*)(xn + (size_t)(2*kp)*HWX + p0 + c4*4);
    f32x4 c = *(const f32x4*)(xn + (size_t)(2*kp+1)*HWX + p0 + c4*4);
    int unit = kp >> 2, off = kp & 3;
    #pragma unroll
    for (int j=0;j<4;j++) {
      int pos = c4*4 + j;
      unsigned dd = (unsigned)f16_bits(a[j]) | ((unsigned)f16_bits(c[j]) << 16);
      *(unsigned*)&sX[pos*256 + ((unit ^ (pos & 31)) << 3) + off*2] = dd;
    }
  }
  __syncthreads();

  f32x4 fzero = {0.f,0.f,0.f,0.f};
  f32x4 acc[4][3];                  // [pos-tile][oc-tile]
  #pragma unroll
  for (int pt=0;pt<4;pt++)
    #pragma unroll
    for (int ot=0;ot<3;ot++) acc[pt][ot] = fzero;

  int ocb = w*48;
  half8 B3[3];
  #pragma unroll
  for (int ot=0;ot<3;ot++)
    B3[ot] = ld_half8(wh + (size_t)(ocb + ot*16 + col)*CIN + quad*8);   // ks=0
  #pragma unroll
  for (int ks=0; ks<8; ks++) {
    half8 B3n[3];
    if (ks < 7) {
      #pragma unroll
      for (int ot=0;ot<3;ot++)
        B3n[ot] = ld_half8(wh + (size_t)(ocb + ot*16 + col)*CIN + (ks+1)*32 + quad*8);
    }
    half8 A4[4];
    #pragma unroll
    for (int pt=0;pt<4;pt++) {
      int pos = pt*16 + col;
      A4[pt] = ld_half8(&sX[pos*256 + (((ks*4 + quad) ^ (pos & 31)) << 3)]);
    }
    #pragma unroll
    for (int pt=0;pt<4;pt++)
      #pragma unroll
      for (int ot=0;ot<3;ot++)
        acc[pt][ot] = __builtin_amdgcn_mfma_f32_16x16x32_f16(A4[pt], B3[ot], acc[pt][ot], 0, 0, 0);
    if (ks < 7) {
      #pragma unroll
      for (int ot=0;ot<3;ot++) B3[ot] = B3n[ot];
    }
  }
  __syncthreads();   // all sX reads done; region reused as sQr

  // epilogue: bias+ReLU; feat (oc<256) direct 8B stores; q (oc>=256) via LDS transpose
  float bv[3];
  #pragma unroll
  for (int ot=0;ot<3;ot++) bv[ot] = bias[ocb + ot*16 + col];
  #pragma unroll
  for (int pt=0;pt<4;pt++)
    #pragma unroll
    for (int ot=0;ot<3;ot++) {
      int oc = ocb + ot*16 + col;
      alignas(8) unsigned short u4[4];
      #pragma unroll
      for (int r=0;r<4;r++)
        u4[r] = f16_bits(fmaxf(acc[pt][ot][r] + bv[ot], 0.f));
      if (oc < CF) {
        *(u32x2*)(feat + (size_t)n*CF*HWX + (size_t)oc*HWX + p0 + pt*16 + quad*4) =
            *(const u32x2*)u4;
      } else {
        int cc = oc - CF;
        #pragma unroll
        for (int r=0;r<4;r++)
          sQr[pt*16 + quad*4 + r][cc] = u4[r];
      }
    }
  __syncthreads();

  // q readback + row norms: t<256: pos = t>>2 (64), seg = t&3 (32 c each)
  if (t < 256) {
    int pos = t >> 2, seg = t & 3;
    const unsigned short* src = &sQr[pos][seg*32];
    unsigned short* dst = q + ((size_t)n*HWX + p0 + pos)*CA + seg*32;
    float s2 = 0.f;
    #pragma unroll
    for (int u=0;u<4;u++) {
      short8 v = *(const short8*)(src + u*8);
      *(short8*)(dst + u*8) = v;
      half8 h = __builtin_bit_cast(half8, v);
      #pragma unroll
      for (int e=0;e<8;e++) { float fe = (float)h[e]; s2 += fe*fe; }
    }
    s2 += __shfl_xor(s2, 1, 64);
    s2 += __shfl_xor(s2, 2, 64);
    if (seg == 0) normq[(size_t)n*HWX + p0 + pos] = sqrtf(s2);
    float mx = s2;
    mx = fmaxf(mx, __shfl_xor(mx, 4, 64));
    mx = fmaxf(mx, __shfl_xor(mx, 8, 64));
    mx = fmaxf(mx, __shfl_xor(mx, 16, 64));
    mx = fmaxf(mx, __shfl_xor(mx, 32, 64));
    if (lane == 0) sGm[t >> 6] = sqrtf(mx);
  }
  __syncthreads();
  if (t == 0) {
    float m01 = fmaxf(sGm[0], sGm[1]);
    float m23 = fmaxf(sGm[2], sGm[3]);
    atomicMax(Gmax + n, __float_as_uint(fmaxf(m01, m23)));
  }
}

// ---------------- kernel 3: flash attention, BN=128, two barriers/iter ----------------
// EXACT R2 kernel (measured 183-185us three times; every structural variant was null
// or worse: R6 reg-cliff, R9 one-barrier dbuf -13%). g2l16 sQ pipeline = the latency
// hider (R1: direct-L2 QK collapses MfmaUtil 24->11). pad-132 sP conflict-free
// (SQ_LDS_BANK_CONFLICT == 0 measured). setprio kept (null but harmless).
__global__ __launch_bounds__(512, 4) void flash_k(
    const unsigned short* __restrict__ q, const unsigned short* __restrict__ feat,
    const float* __restrict__ mask, const float* __restrict__ normq,
    const unsigned* __restrict__ Gmax, float* __restrict__ out) {
  __shared__ alignas(16) unsigned short sQ[128*128];  // j-tile q fp16, octet-swizzled
  __shared__ alignas(16) unsigned short sP[64][132];  // P (A-layout), pad 132
  __shared__ float sM[128];
  __shared__ float sL[2][64];
  int b = blockIdx.x;
  int n = b & 7, it = b >> 3;         // n == XCD for L2 locality
  int i0 = it * 64;
  int t = threadIdx.x;
  int w = t >> 6, lane = t & 63, quad = lane >> 4, col = lane & 15;
  int wq = w & 3, wh = w >> 2;
  const unsigned short* q_n = q + (size_t)n*HWX*CA;
  const unsigned short* f_n = feat + (size_t)n*CF*HWX;
  const float* m_n = mask + (size_t)n*HWX;
  const int rloc = t >> 4 & 31, oct16 = t & 15;
  const float inv_s = 1.0f/(1e-8f + sqrtf(128.0f));

  auto stage_Q = [&](int j0) {
    #pragma unroll
    for (int c=0;c<4;c++) {
      int row = c*32 + rloc;
      int og = oct16 ^ (row & 15);
      g2l16(q_n + (size_t)(j0+row)*CA + og*8, &sQ[(size_t)row*128 + oct16*8]);
    }
    if (t < 32) g2l16(m_n + j0 + t*4, &sM[t*4]);
  };

  // A fragments for QK (this wave's 16 i rows)
  half8 ah[4];
  {
    int arow = i0 + wq*16 + col;
    #pragma unroll
    for (int ks=0; ks<4; ks++)
      ah[ks] = ld_half8(q_n + (size_t)arow*CA + ks*32 + quad*8);
  }
  // per-row exp shift: C_i - 5 (max-free softmax via Cauchy-Schwarz bound)
  float Gn = __uint_as_float(Gmax[n]);
  float cvals[4];
  #pragma unroll
  for (int r=0;r<4;r++)
    cvals[r] = normq[(size_t)n*HWX + i0 + wq*16 + quad*4 + r] * Gn * inv_s - 5.0f;

  f32x4 fzero = {0.f,0.f,0.f,0.f};
  f32x4 o[4][2];                      // [i-group][c-tile], c-slab = w*32
  #pragma unroll
  for (int ig=0;ig<4;ig++) { o[ig][0] = fzero; o[ig][1] = fzero; }
  float lrun[4] = {0.f,0.f,0.f,0.f};

  stage_Q(0);
  #pragma unroll 1
  for (int ji = 0; ji < 32; ji++) {
    int j0 = ji*128;
    __syncthreads();                  // A: sQ(ji)+sM(ji) ready; PV(ji-1) done with sP

    // prefetch PV B-frags for ks2=0,1 (consumed after barrier B; L2 latency hides
    // under QK+softmax). ks2=2,3 loaded at PV start to cap live registers.
    half8 bF01[2][2];
    #pragma unroll
    for (int ks2=0;ks2<2;ks2++)
      #pragma unroll
      for (int ct=0;ct<2;ct++) {
        int c = w*32 + ct*16 + col;
        bF01[ks2][ct] = ld_half8(f_n + (size_t)c*HWX + j0 + ks2*32 + quad*8);
      }

    // ---- QK^T: S[16 i x 64 j] (this wave's j-half), 4 indep chains of 4
    f32x4 s[4];
    #pragma unroll
    for (int jt=0;jt<4;jt++) s[jt] = fzero;
    __builtin_amdgcn_s_setprio(1);
    #pragma unroll
    for (int jt=0;jt<4;jt++) {
      int rowj = wh*64 + jt*16 + col;
      #pragma unroll
      for (int ks=0; ks<4; ks++) {
        int slot = (ks*4 + quad) ^ (rowj & 15);
        half8 bq = ld_half8(&sQ[rowj*128 + slot*8]);
        s[jt] = __builtin_amdgcn_mfma_f32_16x16x32_f16(ah[ks], bq, s[jt], 0, 0, 0);
      }
    }
    __builtin_amdgcn_s_setprio(0);

    // ---- max-free softmax: P = exp(E*inv_s + maskterm - C_i + 5); l += P
    // scalar b16 stores at stride 132 -> conflict-free (quads on banks 0/8/16/24)
    #pragma unroll
    for (int jt=0;jt<4;jt++) {
      float mj = (sM[wh*64 + jt*16 + col] - 1.f) * 1e8f;
      #pragma unroll
      for (int r=0;r<4;r++) {
        float p = __expf(s[jt][r]*inv_s + mj - cvals[r]);
        lrun[r] += p;
        sP[wq*16 + quad*4 + r][wh*64 + jt*16 + col] = f16_bits(p);
      }
    }

    __syncthreads();                  // B: sP visible; QK reads of sQ done
    if (ji + 1 < 32) stage_Q(j0+128); // overlaps PV, drained at next barrier A

    // ---- PV: O[64 i x 32 c] for this wave's c-slab, K=128
    half8 bF23[2][2];
    #pragma unroll
    for (int ks2=0;ks2<2;ks2++)
      #pragma unroll
      for (int ct=0;ct<2;ct++) {
        int c = w*32 + ct*16 + col;
        bF23[ks2][ct] = ld_half8(f_n + (size_t)c*HWX + j0 + (ks2+2)*32 + quad*8);
      }
    __builtin_amdgcn_s_setprio(1);
    #pragma unroll
    for (int ks2=0; ks2<4; ks2++) {
      half8 aP[4];
      #pragma unroll
      for (int ig=0;ig<4;ig++) {
        const unsigned short* pp = &sP[ig*16 + col][ks2*32 + quad*8];
        s16x4 lo = *(const s16x4*)pp;        // rows 8B-aligned (264B stride)
        s16x4 hi = *(const s16x4*)(pp + 4);
        short8 vv = __builtin_shufflevector(lo, hi, 0,1,2,3,4,5,6,7);
        aP[ig] = __builtin_bit_cast(half8, vv);
      }
      #pragma unroll
      for (int ct=0;ct<2;ct++) {
        half8 bF = (ks2 < 2) ? bF01[ks2][ct] : bF23[ks2-2][ct];
        #pragma unroll
        for (int ig=0;ig<4;ig++)
          o[ig][ct] = __builtin_amdgcn_mfma_f32_16x16x32_f16(aP[ig], bF, o[ig][ct], 0, 0, 0);
      }
    }
    __builtin_amdgcn_s_setprio(0);
  }

  // ---- final l: reduce 16 j-cols in-wave, combine halves via LDS
  #pragma unroll
  for (int r=0;r<4;r++) {
    float ss = lrun[r];
    ss += __shfl_xor(ss, 1, 64);
    ss += __shfl_xor(ss, 2, 64);
    ss += __shfl_xor(ss, 4, 64);
    ss += __shfl_xor(ss, 8, 64);
    lrun[r] = ss;
  }
  #pragma unroll
  for (int r=0;r<4;r++)
    if (col == 0) sL[wh][wq*16 + quad*4 + r] = lrun[r];
  __syncthreads();
  #pragma unroll
  for (int ig=0;ig<4;ig++) {
    int base = ig*16 + quad*4;
    f32x4 l0 = *(const f32x4*)&sL[0][base];
    f32x4 l1 = *(const f32x4*)&sL[1][base];
    f32x4 mv = *(const f32x4*)(m_n + i0 + base);
    f32x4 minv;
    #pragma unroll
    for (int r=0;r<4;r++) minv[r] = mv[r] / (l0[r] + l1[r]);
    #pragma unroll
    for (int ct=0;ct<2;ct++) {
      int c = w*32 + ct*16 + col;
      f32x4 v;
      #pragma unroll
      for (int r=0;r<4;r++) v[r] = o[ig][ct][r] * minv[r];
      *(f32x4*)(out + ((size_t)n*CF + c)*HWX + i0 + base) = v;
    }
  }
}

extern "C" void kernel_launch(void* const* d_in, const int* in_sizes, int n_in,
                              void* d_out, int out_size, void* d_ws, size_t ws_size,
                              hipStream_t stream) {
  const float* x    = (const float*)d_in[0];
  const float* mask = (const float*)d_in[1];
  const float* rw   = (const float*)d_in[2];
  const float* rg   = (const float*)d_in[3];
  const float* rb   = (const float*)d_in[4];
  const float* rm   = (const float*)d_in[5];
  const float* rv   = (const float*)d_in[6];
  const float* aw   = (const float*)d_in[7];
  const float* ag   = (const float*)d_in[8];
  const float* ab   = (const float*)d_in[9];
  const float* am   = (const float*)d_in[10];
  const float* av   = (const float*)d_in[11];
  float* out = (float*)d_out;
  char* ws = (char*)d_ws;
  unsigned short* wh = (unsigned short*)(ws + OFF_WH);
  float* bias = (float*)(ws + OFF_BIAS);
  unsigned short* feat = (unsigned short*)(ws + OFF_FEAT);
  unsigned short* q    = (unsigned short*)(ws + OFF_Q);
  float* normq = (float*)(ws + OFF_NORM);
  unsigned* Gmax = (unsigned*)(ws + OFF_G);

  hipLaunchKernelGGL(fold_bn_k, dim3(CT), dim3(CIN), 0, stream,
                     rw, rg, rb, rm, rv, aw, ag, ab, am, av, wh, bias, Gmax);
  hipLaunchKernelGGL(conv_k, dim3(512), dim3(512), 0, stream,
                     x, wh, bias, feat, q, normq, Gmax);
  hipLaunchKernelGGL(flash_k, dim3(512), dim3(512), 0, stream,
                     q, feat, mask, normq, Gmax, out);
}